// Round 1
// baseline (548.629 us; speedup 1.0000x reference)
//
#include <hip/hip_runtime.h>
#include <math.h>

#define HEADS 4
#define CH 64
#define HC 256          // HEADS*CH
#define SLOPE 0.2f

__device__ __forceinline__ float4 ld4(const float* p){ return *(const float4*)p; }
__device__ __forceinline__ void st4(float* p, float4 v){ *(float4*)p = v; }
__device__ __forceinline__ float lrelu(float x){ return x > 0.f ? x : SLOPE * x; }

// ---------------- GEMM1: h = x @ W   [M,256] x [256,256] ----------------
#define BM 64
#define BN 64
#define BK 16
__global__ __launch_bounds__(256) void k_gemm1(const float* __restrict__ A,
    const float* __restrict__ B, float* __restrict__ C, int M) {
  __shared__ float As[BK][BM+4];
  __shared__ float Bs[BK][BN+4];
  int t = threadIdx.x;
  int tx = t & 15, ty = t >> 4;
  int row0 = blockIdx.y * BM, col0 = blockIdx.x * BN;
  float acc[4][4];
  #pragma unroll
  for (int i=0;i<4;i++)
    #pragma unroll
    for (int j=0;j<4;j++) acc[i][j]=0.f;
  int lm = t >> 2, lk = (t & 3) * 4;   // A-tile load coords
  int br = t >> 4, bc = (t & 15) * 4;  // B-tile load coords
  for (int kk = 0; kk < 256; kk += BK) {
    float4 av = make_float4(0.f,0.f,0.f,0.f);
    if (row0 + lm < M) av = ld4(&A[(size_t)(row0+lm)*256 + kk + lk]);
    As[lk+0][lm]=av.x; As[lk+1][lm]=av.y; As[lk+2][lm]=av.z; As[lk+3][lm]=av.w;
    float4 bv = ld4(&B[(size_t)(kk+br)*256 + col0 + bc]);
    st4(&Bs[br][bc], bv);
    __syncthreads();
    #pragma unroll
    for (int k=0;k<BK;k++){
      float ar[4], brr[4];
      #pragma unroll
      for (int i=0;i<4;i++) ar[i]=As[k][ty*4+i];
      #pragma unroll
      for (int j=0;j<4;j++) brr[j]=Bs[k][tx*4+j];
      #pragma unroll
      for (int i=0;i<4;i++)
        #pragma unroll
        for (int j=0;j<4;j++)
          acc[i][j] += ar[i]*brr[j];
    }
    __syncthreads();
  }
  #pragma unroll
  for (int i=0;i<4;i++){
    int row = row0 + ty*4 + i;
    if (row < M) {
      float4 v = make_float4(acc[i][0],acc[i][1],acc[i][2],acc[i][3]);
      st4(&C[(size_t)row*256 + col0 + tx*4], v);
    }
  }
}

// ---------------- attention coefficients a_src/a_dst [N,4] ----------------
__global__ __launch_bounds__(256) void k_attn(const float* __restrict__ h,
    const float* __restrict__ att_src, const float* __restrict__ att_dst,
    float* __restrict__ a_src, float* __restrict__ a_dst, int n) {
  int gid = blockIdx.x*256 + threadIdx.x;
  int node = gid >> 6;
  int lane = threadIdx.x & 63;
  if (node >= n) return;
  float4 v = ld4(&h[(size_t)node*HC + 4*lane]);
  int hd = lane >> 4, co = (lane & 15) * 4;
  float4 as = ld4(&att_src[hd*CH + co]);
  float4 ad = ld4(&att_dst[hd*CH + co]);
  float ps = v.x*as.x + v.y*as.y + v.z*as.z + v.w*as.w;
  float pd = v.x*ad.x + v.y*ad.y + v.z*ad.z + v.w*ad.w;
  #pragma unroll
  for (int m=8; m>=1; m>>=1) { ps += __shfl_xor(ps, m); pd += __shfl_xor(pd, m); }
  if ((lane & 15) == 0) { a_src[node*4+hd] = ps; a_dst[node*4+hd] = pd; }
}

// ---------------- CSR build ----------------
__global__ void k_init_count(int* __restrict__ count, int n) {
  int i = blockIdx.x*256 + threadIdx.x;
  if (i < n) count[i] = 1;               // self-loop
}
__global__ void k_count(const int* __restrict__ ei, int* __restrict__ count, int E) {
  int e = blockIdx.x*256 + threadIdx.x;
  if (e < E) atomicAdd(&count[ei[E+e]], 1);
}
__global__ __launch_bounds__(256) void k_scan1(const int* __restrict__ count,
    int* __restrict__ excl, int* __restrict__ partial, int n) {
  __shared__ int sd[256];
  int t = threadIdx.x, i = blockIdx.x*256 + t;
  int v = (i < n) ? count[i] : 0;
  sd[t] = v; __syncthreads();
  for (int off=1; off<256; off<<=1) {
    int x = (t >= off) ? sd[t-off] : 0;
    __syncthreads();
    sd[t] += x;
    __syncthreads();
  }
  if (i < n) excl[i] = sd[t] - v;
  if (t == 255) partial[blockIdx.x] = sd[255];
}
__global__ __launch_bounds__(256) void k_scan2(int* __restrict__ partial, int nb) {
  __shared__ int sd[256];
  int t = threadIdx.x;
  int v = (t < nb) ? partial[t] : 0;
  sd[t] = v; __syncthreads();
  for (int off=1; off<256; off<<=1) {
    int x = (t >= off) ? sd[t-off] : 0;
    __syncthreads();
    sd[t] += x;
    __syncthreads();
  }
  partial[t] = sd[t] - v;
}
__global__ void k_scan3(int* __restrict__ row_start, int* __restrict__ cursor,
    const int* __restrict__ partial, const int* __restrict__ count, int n) {
  int i = blockIdx.x*256 + threadIdx.x;
  if (i < n) {
    int v = row_start[i] + partial[blockIdx.x];
    row_start[i] = v;
    cursor[i] = v;
    if (i == n-1) row_start[n] = v + count[i];
  }
}
__global__ void k_fill(const int* __restrict__ ei, int* __restrict__ cursor,
    int* __restrict__ csr, int E, int n) {
  int t = blockIdx.x*256 + threadIdx.x;
  if (t < E + n) {
    int s, d;
    if (t < E) { s = ei[t]; d = ei[E+t]; } else { s = t - E; d = s; }
    int p = atomicAdd(&cursor[d], 1);
    csr[p] = s;
  }
}

// ---------------- GAT softmax + aggregate, one block per dst ----------------
__global__ __launch_bounds__(256) void k_gat(const float* __restrict__ hfeat,
    const float4* __restrict__ a_src, const float4* __restrict__ a_dst,
    const int* __restrict__ row_start, const int* __restrict__ csr,
    const float* __restrict__ bias, float* __restrict__ out_conv) {
  int n = blockIdx.x;
  int t = threadIdx.x;
  int g = t >> 6, lane = t & 63;
  int hd_c = lane >> 4;                 // head owning this thread's 4 channels
  int beg = row_start[n];
  int deg = row_start[n+1] - beg;

  __shared__ int   s_src[256];
  __shared__ float s_p[4][256];
  __shared__ float s_m[4], s_l[4], s_scale[4];
  __shared__ float s_part[4][256];

  if (t < 4) { s_m[t] = -INFINITY; s_l[t] = 0.f; }
  float4 ad = a_dst[n];
  float4 acc = make_float4(0.f,0.f,0.f,0.f);

  for (int cb = 0; cb < deg; cb += 256) {
    int cnt = min(256, deg - cb);
    float4 ev = make_float4(-INFINITY,-INFINITY,-INFINITY,-INFINITY);
    if (t < cnt) {
      int s = csr[beg + cb + t];
      s_src[t] = s;
      float4 as = a_src[s];
      ev.x = lrelu(as.x + ad.x);
      ev.y = lrelu(as.y + ad.y);
      ev.z = lrelu(as.z + ad.z);
      ev.w = lrelu(as.w + ad.w);
    }
    s_p[0][t]=ev.x; s_p[1][t]=ev.y; s_p[2][t]=ev.z; s_p[3][t]=ev.w;
    __syncthreads();
    // per-head max: wave g reduces head g
    float mv = fmaxf(fmaxf(s_p[g][lane], s_p[g][lane+64]),
                     fmaxf(s_p[g][lane+128], s_p[g][lane+192]));
    #pragma unroll
    for (int m=32; m>=1; m>>=1) mv = fmaxf(mv, __shfl_xor(mv, m));
    if (lane == 0) {
      float om = s_m[g];
      float nm = fmaxf(om, mv);
      s_scale[g] = __expf(om - nm);
      s_m[g] = nm;
    }
    __syncthreads();
    {
      float sc = s_scale[hd_c];
      acc.x *= sc; acc.y *= sc; acc.z *= sc; acc.w *= sc;
    }
    float4 p = make_float4(0.f,0.f,0.f,0.f);
    if (t < cnt) {
      p.x = __expf(ev.x - s_m[0]);
      p.y = __expf(ev.y - s_m[1]);
      p.z = __expf(ev.z - s_m[2]);
      p.w = __expf(ev.w - s_m[3]);
    }
    s_p[0][t]=p.x; s_p[1][t]=p.y; s_p[2][t]=p.z; s_p[3][t]=p.w;
    __syncthreads();
    float sv = s_p[g][lane] + s_p[g][lane+64] + s_p[g][lane+128] + s_p[g][lane+192];
    #pragma unroll
    for (int m=32; m>=1; m>>=1) sv += __shfl_xor(sv, m);
    if (lane == 0) s_l[g] = s_l[g]*s_scale[g] + sv;
    // aggregate: group g takes edges j = g, g+4, ...
    for (int j = g; j < cnt; j += 4) {
      int s = s_src[j];
      float pw = s_p[hd_c][j];
      float4 hv = ld4(&hfeat[(size_t)s*HC + 4*lane]);
      acc.x += pw*hv.x; acc.y += pw*hv.y; acc.z += pw*hv.z; acc.w += pw*hv.w;
    }
    __syncthreads();
  }
  st4(&s_part[g][lane*4], acc);
  __syncthreads();
  if (t < 64) {
    float4 r0 = ld4(&s_part[0][t*4]);
    float4 r1 = ld4(&s_part[1][t*4]);
    float4 r2 = ld4(&s_part[2][t*4]);
    float4 r3 = ld4(&s_part[3][t*4]);
    float4 r = make_float4(r0.x+r1.x+r2.x+r3.x, r0.y+r1.y+r2.y+r3.y,
                           r0.z+r1.z+r2.z+r3.z, r0.w+r1.w+r2.w+r3.w);
    int hh = t >> 4;
    float invl = 1.f / s_l[hh];
    float4 b = ld4(&bias[t*4]);
    r.x = fmaxf(r.x*invl + b.x, 0.f);
    r.y = fmaxf(r.y*invl + b.y, 0.f);
    r.z = fmaxf(r.z*invl + b.z, 0.f);
    r.w = fmaxf(r.w*invl + b.w, 0.f);
    st4(&out_conv[(size_t)n*HC + t*4], r);
  }
}

// ---------------- fused MLP: relu(X@W1+b1)@W2+b2 ----------------
#define MROWS 16
__global__ __launch_bounds__(256) void k_mlp(const float* __restrict__ X,
    const float* __restrict__ W1, const float* __restrict__ b1,
    const float* __restrict__ W2, const float* __restrict__ b2,
    float* __restrict__ out, int M) {
  __shared__ float xs[MROWS][260];
  __shared__ float hs[MROWS][64];
  int rowb = blockIdx.x * MROWS;
  int t = threadIdx.x;
  // stage X tile (16 rows x 256)
  #pragma unroll
  for (int i=0;i<4;i++){
    int f = t + 256*i;           // float4 index 0..1023
    int r = f >> 6, c4 = (f & 63) * 4;
    float4 v = make_float4(0.f,0.f,0.f,0.f);
    if (rowb + r < M) v = ld4(&X[(size_t)(rowb+r)*HC + c4]);
    st4(&xs[r][c4], v);
  }
  __syncthreads();
  // stage 1: hid = relu(X@W1+b1); thread -> (row r, 4 cols j4)
  {
    int r = t >> 4, j4 = (t & 15) * 4;
    float4 acc = ld4(&b1[j4]);
    for (int k=0;k<256;k++){
      float xv = xs[r][k];
      float4 w = ld4(&W1[(size_t)k*64 + j4]);
      acc.x += xv*w.x; acc.y += xv*w.y; acc.z += xv*w.z; acc.w += xv*w.w;
    }
    acc.x = fmaxf(acc.x, 0.f); acc.y = fmaxf(acc.y, 0.f);
    acc.z = fmaxf(acc.z, 0.f); acc.w = fmaxf(acc.w, 0.f);
    st4(&hs[r][j4], acc);
  }
  __syncthreads();
  // stage 2: out = hid@W2+b2
  {
    int o = t & 63, rr = t >> 6;
    if (o < 40) {
      #pragma unroll
      for (int p=0;p<4;p++){
        int r2 = rr + 4*p;
        if (rowb + r2 < M) {
          float a = b2[o];
          for (int k=0;k<64;k++) a += hs[r2][k]*W2[k*40 + o];
          out[(size_t)(rowb+r2)*40 + o] = a;
        }
      }
    }
  }
}

extern "C" void kernel_launch(void* const* d_in, const int* in_sizes, int n_in,
                              void* d_out, int out_size, void* d_ws, size_t ws_size,
                              hipStream_t stream) {
  const int Nn = in_sizes[0] / HC;   // 50000
  const int E  = in_sizes[1] / 2;    // 800000
  const float* x        = (const float*)d_in[0];
  const int*   ei       = (const int*)d_in[1];
  const float* W        = (const float*)d_in[2];
  const float* att_src  = (const float*)d_in[3];
  const float* att_dst  = (const float*)d_in[4];
  const float* biasconv = (const float*)d_in[5];
  const float* W1       = (const float*)d_in[6];
  const float* b1       = (const float*)d_in[7];
  const float* W2       = (const float*)d_in[8];
  const float* b2       = (const float*)d_in[9];
  float* out = (float*)d_out;

  size_t off = 0;
  auto alloc = [&](size_t bytes)->void* {
    void* p = (void*)((char*)d_ws + off);
    off += (bytes + 255) & ~(size_t)255;
    return p;
  };
  float* h        = (float*)alloc((size_t)Nn*HC*sizeof(float));
  float* outc     = (float*)alloc((size_t)Nn*HC*sizeof(float));
  float* a_src_v  = (float*)alloc((size_t)Nn*4*sizeof(float));
  float* a_dst_v  = (float*)alloc((size_t)Nn*4*sizeof(float));
  int*   count    = (int*)alloc((size_t)Nn*sizeof(int));
  int*   rowstart = (int*)alloc((size_t)(Nn+1)*sizeof(int));
  int*   cursor   = (int*)alloc((size_t)Nn*sizeof(int));
  int*   partial  = (int*)alloc(256*sizeof(int));
  int*   csr      = (int*)alloc((size_t)(E+Nn)*sizeof(int));
  (void)ws_size; (void)n_in; (void)out_size;

  dim3 blk(256);
  k_gemm1<<<dim3(HC/BN, (Nn+BM-1)/BM), blk, 0, stream>>>(x, W, h, Nn);
  k_attn<<<dim3((Nn+3)/4), blk, 0, stream>>>(h, att_src, att_dst, a_src_v, a_dst_v, Nn);
  k_init_count<<<dim3((Nn+255)/256), blk, 0, stream>>>(count, Nn);
  k_count<<<dim3((E+255)/256), blk, 0, stream>>>(ei, count, E);
  int nb = (Nn+255)/256;
  k_scan1<<<dim3(nb), blk, 0, stream>>>(count, rowstart, partial, Nn);
  k_scan2<<<dim3(1), blk, 0, stream>>>(partial, nb);
  k_scan3<<<dim3(nb), blk, 0, stream>>>(rowstart, cursor, partial, count, Nn);
  k_fill<<<dim3((E+Nn+255)/256), blk, 0, stream>>>(ei, cursor, csr, E, Nn);
  k_gat<<<dim3(Nn), blk, 0, stream>>>(h, (const float4*)a_src_v, (const float4*)a_dst_v,
                                      rowstart, csr, biasconv, outc);
  k_mlp<<<dim3((Nn+MROWS-1)/MROWS), blk, 0, stream>>>(outc, W1, b1, W2, b2, out, Nn);
}

// Round 2
// 493.289 us; speedup vs baseline: 1.1122x; 1.1122x over previous
//
#include <hip/hip_runtime.h>
#include <math.h>

#define HEADS 4
#define CH 64
#define HC 256          // HEADS*CH
#define SLOPE 0.2f

__device__ __forceinline__ float4 ld4(const float* p){ return *(const float4*)p; }
__device__ __forceinline__ void st4(float* p, float4 v){ *(float4*)p = v; }
__device__ __forceinline__ float lrelu(float x){ return x > 0.f ? x : SLOPE * x; }

// ---------------- GEMM1: h = x @ W   [M,256] x [256,256] ----------------
#define BM 64
#define BN 64
#define BK 16
__global__ __launch_bounds__(256) void k_gemm1(const float* __restrict__ A,
    const float* __restrict__ B, float* __restrict__ C, int M) {
  __shared__ float As[BK][BM+4];
  __shared__ float Bs[BK][BN+4];
  int t = threadIdx.x;
  int tx = t & 15, ty = t >> 4;
  int row0 = blockIdx.y * BM, col0 = blockIdx.x * BN;
  float acc[4][4];
  #pragma unroll
  for (int i=0;i<4;i++)
    #pragma unroll
    for (int j=0;j<4;j++) acc[i][j]=0.f;
  int lm = t >> 2, lk = (t & 3) * 4;   // A-tile load coords
  int br = t >> 4, bc = (t & 15) * 4;  // B-tile load coords
  for (int kk = 0; kk < 256; kk += BK) {
    float4 av = make_float4(0.f,0.f,0.f,0.f);
    if (row0 + lm < M) av = ld4(&A[(size_t)(row0+lm)*256 + kk + lk]);
    As[lk+0][lm]=av.x; As[lk+1][lm]=av.y; As[lk+2][lm]=av.z; As[lk+3][lm]=av.w;
    float4 bv = ld4(&B[(size_t)(kk+br)*256 + col0 + bc]);
    st4(&Bs[br][bc], bv);
    __syncthreads();
    #pragma unroll
    for (int k=0;k<BK;k++){
      float ar[4], brr[4];
      #pragma unroll
      for (int i=0;i<4;i++) ar[i]=As[k][ty*4+i];
      #pragma unroll
      for (int j=0;j<4;j++) brr[j]=Bs[k][tx*4+j];
      #pragma unroll
      for (int i=0;i<4;i++)
        #pragma unroll
        for (int j=0;j<4;j++)
          acc[i][j] += ar[i]*brr[j];
    }
    __syncthreads();
  }
  #pragma unroll
  for (int i=0;i<4;i++){
    int row = row0 + ty*4 + i;
    if (row < M) {
      float4 v = make_float4(acc[i][0],acc[i][1],acc[i][2],acc[i][3]);
      st4(&C[(size_t)row*256 + col0 + tx*4], v);
    }
  }
}

// ---------------- attention coefficients a_src/a_dst [N,4] ----------------
__global__ __launch_bounds__(256) void k_attn(const float* __restrict__ h,
    const float* __restrict__ att_src, const float* __restrict__ att_dst,
    float* __restrict__ a_src, float* __restrict__ a_dst, int n) {
  int gid = blockIdx.x*256 + threadIdx.x;
  int node = gid >> 6;
  int lane = threadIdx.x & 63;
  if (node >= n) return;
  float4 v = ld4(&h[(size_t)node*HC + 4*lane]);
  int hd = lane >> 4, co = (lane & 15) * 4;
  float4 as = ld4(&att_src[hd*CH + co]);
  float4 ad = ld4(&att_dst[hd*CH + co]);
  float ps = v.x*as.x + v.y*as.y + v.z*as.z + v.w*as.w;
  float pd = v.x*ad.x + v.y*ad.y + v.z*ad.z + v.w*ad.w;
  #pragma unroll
  for (int m=8; m>=1; m>>=1) { ps += __shfl_xor(ps, m); pd += __shfl_xor(pd, m); }
  if ((lane & 15) == 0) { a_src[node*4+hd] = ps; a_dst[node*4+hd] = pd; }
}

// ---------------- CSR build ----------------
__global__ void k_init_count(int* __restrict__ count, int n) {
  int i = blockIdx.x*256 + threadIdx.x;
  if (i < n) count[i] = 1;               // self-loop
}
__global__ void k_count(const int* __restrict__ ei, int* __restrict__ count, int E) {
  int e = blockIdx.x*256 + threadIdx.x;
  if (e < E) atomicAdd(&count[ei[E+e]], 1);
}
__global__ __launch_bounds__(256) void k_scan1(const int* __restrict__ count,
    int* __restrict__ excl, int* __restrict__ partial, int n) {
  __shared__ int sd[256];
  int t = threadIdx.x, i = blockIdx.x*256 + t;
  int v = (i < n) ? count[i] : 0;
  sd[t] = v; __syncthreads();
  for (int off=1; off<256; off<<=1) {
    int x = (t >= off) ? sd[t-off] : 0;
    __syncthreads();
    sd[t] += x;
    __syncthreads();
  }
  if (i < n) excl[i] = sd[t] - v;
  if (t == 255) partial[blockIdx.x] = sd[255];
}
__global__ __launch_bounds__(256) void k_scan2(int* __restrict__ partial, int nb) {
  __shared__ int sd[256];
  int t = threadIdx.x;
  int v = (t < nb) ? partial[t] : 0;
  sd[t] = v; __syncthreads();
  for (int off=1; off<256; off<<=1) {
    int x = (t >= off) ? sd[t-off] : 0;
    __syncthreads();
    sd[t] += x;
    __syncthreads();
  }
  partial[t] = sd[t] - v;
}
__global__ void k_scan3(int* __restrict__ row_start, int* __restrict__ cursor,
    const int* __restrict__ partial, const int* __restrict__ count, int n) {
  int i = blockIdx.x*256 + threadIdx.x;
  if (i < n) {
    int v = row_start[i] + partial[blockIdx.x];
    row_start[i] = v;
    cursor[i] = v;
    if (i == n-1) row_start[n] = v + count[i];
  }
}
__global__ void k_fill(const int* __restrict__ ei, int* __restrict__ cursor,
    int* __restrict__ csr, int E, int n) {
  int t = blockIdx.x*256 + threadIdx.x;
  if (t < E + n) {
    int s, d;
    if (t < E) { s = ei[t]; d = ei[E+t]; } else { s = t - E; d = s; }
    int p = atomicAdd(&cursor[d], 1);
    csr[p] = s;
  }
}

// ---------------- GAT softmax + aggregate, one WAVE per dst node ----------------
// 4 nodes per 256-thread block; fully wave-synchronous (no __syncthreads).
__global__ __launch_bounds__(256) void k_gat(const float* __restrict__ hfeat,
    const float4* __restrict__ a_src, const float4* __restrict__ a_dst,
    const int* __restrict__ row_start, const int* __restrict__ csr,
    const float* __restrict__ bias, float* __restrict__ out_conv) {
  int w = threadIdx.x >> 6, lane = threadIdx.x & 63;
  int n = blockIdx.x * 4 + w;          // grid = N/4 exactly (N multiple of 4)
  int hd = lane >> 4;                  // head owning channels 4*lane..4*lane+3

  __shared__ float s_p[4][64][4];      // [wave][edge][head]

  float4 ad = a_dst[n];
  float m0=-INFINITY, m1=-INFINITY, m2=-INFINITY, m3=-INFINITY;
  float4 l4 = make_float4(0.f,0.f,0.f,0.f);   // per-lane partial denom per head
  float4 acc = make_float4(0.f,0.f,0.f,0.f);

  int beg = row_start[n];
  int deg = row_start[n+1] - beg;

  for (int cb = 0; cb < deg; cb += 64) {
    int cnt = min(64, deg - cb);
    int s = 0;
    float4 e = make_float4(-INFINITY,-INFINITY,-INFINITY,-INFINITY);
    if (lane < cnt) {
      s = csr[beg + cb + lane];
      float4 as = a_src[s];
      e.x = lrelu(as.x + ad.x);
      e.y = lrelu(as.y + ad.y);
      e.z = lrelu(as.z + ad.z);
      e.w = lrelu(as.w + ad.w);
    }
    // chunk max per head across the wave
    float4 cm = e;
    #pragma unroll
    for (int d=32; d>=1; d>>=1) {
      cm.x = fmaxf(cm.x, __shfl_xor(cm.x, d));
      cm.y = fmaxf(cm.y, __shfl_xor(cm.y, d));
      cm.z = fmaxf(cm.z, __shfl_xor(cm.z, d));
      cm.w = fmaxf(cm.w, __shfl_xor(cm.w, d));
    }
    float nm0 = fmaxf(m0, cm.x), nm1 = fmaxf(m1, cm.y);
    float nm2 = fmaxf(m2, cm.z), nm3 = fmaxf(m3, cm.w);
    float sc0 = __expf(m0-nm0), sc1 = __expf(m1-nm1);
    float sc2 = __expf(m2-nm2), sc3 = __expf(m3-nm3);
    m0=nm0; m1=nm1; m2=nm2; m3=nm3;
    float sch = hd==0 ? sc0 : hd==1 ? sc1 : hd==2 ? sc2 : sc3;
    acc.x *= sch; acc.y *= sch; acc.z *= sch; acc.w *= sch;
    float4 p = make_float4(0.f,0.f,0.f,0.f);
    if (lane < cnt) {
      p.x = __expf(e.x - nm0);
      p.y = __expf(e.y - nm1);
      p.z = __expf(e.z - nm2);
      p.w = __expf(e.w - nm3);
    }
    l4.x = l4.x*sc0 + p.x;
    l4.y = l4.y*sc1 + p.y;
    l4.z = l4.z*sc2 + p.z;
    l4.w = l4.w*sc3 + p.w;
    st4(&s_p[w][lane][0], p);          // wave-local; compiler inserts lgkmcnt waits
    for (int j = 0; j < cnt; j++) {
      int sj = __shfl(s, j);
      float pw = s_p[w][j][hd];
      float4 hv = ld4(&hfeat[(size_t)sj*HC + 4*lane]);
      acc.x += pw*hv.x; acc.y += pw*hv.y; acc.z += pw*hv.z; acc.w += pw*hv.w;
    }
  }
  // total denom per head
  #pragma unroll
  for (int d=32; d>=1; d>>=1) {
    l4.x += __shfl_xor(l4.x, d);
    l4.y += __shfl_xor(l4.y, d);
    l4.z += __shfl_xor(l4.z, d);
    l4.w += __shfl_xor(l4.w, d);
  }
  float lh = hd==0 ? l4.x : hd==1 ? l4.y : hd==2 ? l4.z : l4.w;
  float inv = 1.f / lh;
  float4 b = ld4(&bias[4*lane]);
  float4 r;
  r.x = fmaxf(acc.x*inv + b.x, 0.f);
  r.y = fmaxf(acc.y*inv + b.y, 0.f);
  r.z = fmaxf(acc.z*inv + b.z, 0.f);
  r.w = fmaxf(acc.w*inv + b.w, 0.f);
  st4(&out_conv[(size_t)n*HC + 4*lane], r);
}

// ---------------- lin1: hid = relu(X@W1 + b1)  [M,256]x[256,64] ----------------
__global__ __launch_bounds__(256) void k_lin1(const float* __restrict__ A,
    const float* __restrict__ B, const float* __restrict__ b1,
    float* __restrict__ C, int M) {
  __shared__ float As[BK][BM+4];
  __shared__ float Bs[BK][68];
  int t = threadIdx.x;
  int tx = t & 15, ty = t >> 4;
  int row0 = blockIdx.x * BM;
  float acc[4][4];
  #pragma unroll
  for (int i=0;i<4;i++)
    #pragma unroll
    for (int j=0;j<4;j++) acc[i][j]=0.f;
  int lm = t >> 2, lk = (t & 3) * 4;
  int br = t >> 4, bc = (t & 15) * 4;
  for (int kk = 0; kk < 256; kk += BK) {
    float4 av = make_float4(0.f,0.f,0.f,0.f);
    if (row0 + lm < M) av = ld4(&A[(size_t)(row0+lm)*256 + kk + lk]);
    As[lk+0][lm]=av.x; As[lk+1][lm]=av.y; As[lk+2][lm]=av.z; As[lk+3][lm]=av.w;
    st4(&Bs[br][bc], ld4(&B[(size_t)(kk+br)*64 + bc]));
    __syncthreads();
    #pragma unroll
    for (int k=0;k<BK;k++){
      float ar[4], brr[4];
      #pragma unroll
      for (int i=0;i<4;i++) ar[i]=As[k][ty*4+i];
      #pragma unroll
      for (int j=0;j<4;j++) brr[j]=Bs[k][tx*4+j];
      #pragma unroll
      for (int i=0;i<4;i++)
        #pragma unroll
        for (int j=0;j<4;j++)
          acc[i][j] += ar[i]*brr[j];
    }
    __syncthreads();
  }
  float4 bb = ld4(&b1[tx*4]);
  #pragma unroll
  for (int i=0;i<4;i++){
    int row = row0 + ty*4 + i;
    if (row < M) {
      float4 v = make_float4(fmaxf(acc[i][0]+bb.x,0.f), fmaxf(acc[i][1]+bb.y,0.f),
                             fmaxf(acc[i][2]+bb.z,0.f), fmaxf(acc[i][3]+bb.w,0.f));
      st4(&C[(size_t)row*64 + tx*4], v);
    }
  }
}

// ---------------- lin2: out = hid@W2 + b2  [M,64]x[64,40] ----------------
__global__ __launch_bounds__(256) void k_lin2(const float* __restrict__ Hd,
    const float* __restrict__ W2, const float* __restrict__ b2,
    float* __restrict__ out, int M) {
  __shared__ float Hs[64][68];
  __shared__ float W2s[64][44];
  int t = threadIdx.x;
  int rowb = blockIdx.x * 64;
  // stage W2 (64x40)
  #pragma unroll
  for (int i=0;i<3;i++){
    int idx = t + 256*i;
    if (idx < 640) {
      int k = idx/10, c4 = (idx%10)*4;
      st4(&W2s[k][c4], ld4(&W2[(size_t)k*40 + c4]));
    }
  }
  // stage hid tile (64x64)
  #pragma unroll
  for (int i=0;i<4;i++){
    int idx = t + 256*i;
    int r = idx >> 4, c4 = (idx & 15)*4;
    float4 v = make_float4(0.f,0.f,0.f,0.f);
    if (rowb + r < M) v = ld4(&Hd[(size_t)(rowb+r)*64 + c4]);
    st4(&Hs[r][c4], v);
  }
  __syncthreads();
  int tx = t & 15, ty = t >> 4;        // tx<10 active for compute
  if (tx < 10) {
    float acc[4][4];
    #pragma unroll
    for (int i=0;i<4;i++)
      #pragma unroll
      for (int j=0;j<4;j++) acc[i][j]=0.f;
    #pragma unroll
    for (int k4=0;k4<16;k4++){
      float4 a[4], wv[4];
      #pragma unroll
      for (int i=0;i<4;i++) a[i] = ld4(&Hs[ty*4+i][k4*4]);
      #pragma unroll
      for (int kk=0;kk<4;kk++) wv[kk] = ld4(&W2s[k4*4+kk][tx*4]);
      #pragma unroll
      for (int i=0;i<4;i++){
        acc[i][0] += a[i].x*wv[0].x + a[i].y*wv[1].x + a[i].z*wv[2].x + a[i].w*wv[3].x;
        acc[i][1] += a[i].x*wv[0].y + a[i].y*wv[1].y + a[i].z*wv[2].y + a[i].w*wv[3].y;
        acc[i][2] += a[i].x*wv[0].z + a[i].y*wv[1].z + a[i].z*wv[2].z + a[i].w*wv[3].z;
        acc[i][3] += a[i].x*wv[0].w + a[i].y*wv[1].w + a[i].z*wv[2].w + a[i].w*wv[3].w;
      }
    }
    float4 bb = ld4(&b2[tx*4]);
    #pragma unroll
    for (int i=0;i<4;i++){
      int row = rowb + ty*4 + i;
      if (row < M) {
        float4 v = make_float4(acc[i][0]+bb.x, acc[i][1]+bb.y,
                               acc[i][2]+bb.z, acc[i][3]+bb.w);
        st4(&out[(size_t)row*40 + tx*4], v);
      }
    }
  }
}

extern "C" void kernel_launch(void* const* d_in, const int* in_sizes, int n_in,
                              void* d_out, int out_size, void* d_ws, size_t ws_size,
                              hipStream_t stream) {
  const int Nn = in_sizes[0] / HC;   // 50000
  const int E  = in_sizes[1] / 2;    // 800000
  const float* x        = (const float*)d_in[0];
  const int*   ei       = (const int*)d_in[1];
  const float* W        = (const float*)d_in[2];
  const float* att_src  = (const float*)d_in[3];
  const float* att_dst  = (const float*)d_in[4];
  const float* biasconv = (const float*)d_in[5];
  const float* W1       = (const float*)d_in[6];
  const float* b1       = (const float*)d_in[7];
  const float* W2       = (const float*)d_in[8];
  const float* b2       = (const float*)d_in[9];
  float* out = (float*)d_out;

  size_t off = 0;
  auto alloc = [&](size_t bytes)->void* {
    void* p = (void*)((char*)d_ws + off);
    off += (bytes + 255) & ~(size_t)255;
    return p;
  };
  float* h        = (float*)alloc((size_t)Nn*HC*sizeof(float));
  float* outc     = (float*)alloc((size_t)Nn*HC*sizeof(float));
  float* hid      = (float*)alloc((size_t)Nn*64*sizeof(float));
  float* a_src_v  = (float*)alloc((size_t)Nn*4*sizeof(float));
  float* a_dst_v  = (float*)alloc((size_t)Nn*4*sizeof(float));
  int*   count    = (int*)alloc((size_t)Nn*sizeof(int));
  int*   rowstart = (int*)alloc((size_t)(Nn+1)*sizeof(int));
  int*   cursor   = (int*)alloc((size_t)Nn*sizeof(int));
  int*   partial  = (int*)alloc(256*sizeof(int));
  int*   csr      = (int*)alloc((size_t)(E+Nn)*sizeof(int));
  (void)ws_size; (void)n_in; (void)out_size;

  dim3 blk(256);
  k_gemm1<<<dim3(HC/BN, (Nn+BM-1)/BM), blk, 0, stream>>>(x, W, h, Nn);
  k_attn<<<dim3((Nn+3)/4), blk, 0, stream>>>(h, att_src, att_dst, a_src_v, a_dst_v, Nn);
  k_init_count<<<dim3((Nn+255)/256), blk, 0, stream>>>(count, Nn);
  k_count<<<dim3((E+255)/256), blk, 0, stream>>>(ei, count, E);
  int nb = (Nn+255)/256;
  k_scan1<<<dim3(nb), blk, 0, stream>>>(count, rowstart, partial, Nn);
  k_scan2<<<dim3(1), blk, 0, stream>>>(partial, nb);
  k_scan3<<<dim3(nb), blk, 0, stream>>>(rowstart, cursor, partial, count, Nn);
  k_fill<<<dim3((E+Nn+255)/256), blk, 0, stream>>>(ei, cursor, csr, E, Nn);
  k_gat<<<dim3(Nn/4), blk, 0, stream>>>(h, (const float4*)a_src_v, (const float4*)a_dst_v,
                                        rowstart, csr, biasconv, outc);
  k_lin1<<<dim3((Nn+BM-1)/BM), blk, 0, stream>>>(outc, W1, b1, hid, Nn);
  k_lin2<<<dim3((Nn+63)/64), blk, 0, stream>>>(hid, W2, b2, out, Nn);
}

// Round 3
// 428.870 us; speedup vs baseline: 1.2792x; 1.1502x over previous
//
#include <hip/hip_runtime.h>
#include <math.h>

#define HEADS 4
#define CH 64
#define HC 256          // HEADS*CH
#define SLOPE 0.2f

__device__ __forceinline__ float4 ld4(const float* p){ return *(const float4*)p; }
__device__ __forceinline__ void st4(float* p, float4 v){ *(float4*)p = v; }
__device__ __forceinline__ float lrelu(float x){ return x > 0.f ? x : SLOPE * x; }
__device__ __forceinline__ unsigned short f2bf(float f){
  union { float f; unsigned int u; } v; v.f = f;
  unsigned int r = v.u + 0x7fffu + ((v.u >> 16) & 1u);   // RNE
  return (unsigned short)(r >> 16);
}
__device__ __forceinline__ float bflo(unsigned int u){
  union { unsigned int u; float f; } v; v.u = u << 16; return v.f;
}
__device__ __forceinline__ float bfhi(unsigned int u){
  union { unsigned int u; float f; } v; v.u = u & 0xffff0000u; return v.f;
}

// ---------------- GEMM1 fused: h_bf16 = bf16(x@W); a_src/a_dst dots ----------------
// grid = (4 head/col tiles, rowTiles). Col tile == one head (C=64).
#define BM 64
#define BN 64
#define BK 16
__global__ __launch_bounds__(256) void k_gemm1(const float* __restrict__ A,
    const float* __restrict__ B, unsigned short* __restrict__ hbf,
    float* __restrict__ a_srcO, float* __restrict__ a_dstO,
    const float* __restrict__ att_src, const float* __restrict__ att_dst, int M) {
  __shared__ float As[BK][BM+4];
  __shared__ float Bs[BK][BN+4];
  int t = threadIdx.x;
  int tx = t & 15, ty = t >> 4;
  int head = blockIdx.x;
  int row0 = blockIdx.y * BM, col0 = head * BN;
  float acc[4][4];
  #pragma unroll
  for (int i=0;i<4;i++)
    #pragma unroll
    for (int j=0;j<4;j++) acc[i][j]=0.f;
  int lm = t >> 2, lk = (t & 3) * 4;   // A-tile load coords
  int br = t >> 4, bc = (t & 15) * 4;  // B-tile load coords
  for (int kk = 0; kk < 256; kk += BK) {
    float4 av = make_float4(0.f,0.f,0.f,0.f);
    if (row0 + lm < M) av = ld4(&A[(size_t)(row0+lm)*256 + kk + lk]);
    As[lk+0][lm]=av.x; As[lk+1][lm]=av.y; As[lk+2][lm]=av.z; As[lk+3][lm]=av.w;
    float4 bv = ld4(&B[(size_t)(kk+br)*256 + col0 + bc]);
    st4(&Bs[br][bc], bv);
    __syncthreads();
    #pragma unroll
    for (int k=0;k<BK;k++){
      float ar[4], brr[4];
      #pragma unroll
      for (int i=0;i<4;i++) ar[i]=As[k][ty*4+i];
      #pragma unroll
      for (int j=0;j<4;j++) brr[j]=Bs[k][tx*4+j];
      #pragma unroll
      for (int i=0;i<4;i++)
        #pragma unroll
        for (int j=0;j<4;j++)
          acc[i][j] += ar[i]*brr[j];
    }
    __syncthreads();
  }
  // epilogue: bf16 h store + per-head attention dots
  float4 asv = ld4(&att_src[head*CH + tx*4]);
  float4 adv = ld4(&att_dst[head*CH + tx*4]);
  #pragma unroll
  for (int i=0;i<4;i++){
    int row = row0 + ty*4 + i;
    float ps = acc[i][0]*asv.x + acc[i][1]*asv.y + acc[i][2]*asv.z + acc[i][3]*asv.w;
    float pd = acc[i][0]*adv.x + acc[i][1]*adv.y + acc[i][2]*adv.z + acc[i][3]*adv.w;
    #pragma unroll
    for (int m=8; m>=1; m>>=1) { ps += __shfl_xor(ps, m); pd += __shfl_xor(pd, m); }
    if (row < M) {
      ushort4 u;
      u.x = f2bf(acc[i][0]); u.y = f2bf(acc[i][1]);
      u.z = f2bf(acc[i][2]); u.w = f2bf(acc[i][3]);
      *(ushort4*)&hbf[(size_t)row*HC + col0 + tx*4] = u;
      if (tx == 0) { a_srcO[row*4+head] = ps; a_dstO[row*4+head] = pd; }
    }
  }
}

// ---------------- CSR build ----------------
__global__ void k_init_count(int* __restrict__ count, int n) {
  int i = blockIdx.x*256 + threadIdx.x;
  if (i < n) count[i] = 1;               // self-loop
}
__global__ void k_count(const int* __restrict__ ei, int* __restrict__ count, int E) {
  int e = blockIdx.x*256 + threadIdx.x;
  if (e < E) atomicAdd(&count[ei[E+e]], 1);
}
__global__ __launch_bounds__(256) void k_scan1(const int* __restrict__ count,
    int* __restrict__ excl, int* __restrict__ partial, int n) {
  __shared__ int sd[256];
  int t = threadIdx.x, i = blockIdx.x*256 + t;
  int v = (i < n) ? count[i] : 0;
  sd[t] = v; __syncthreads();
  for (int off=1; off<256; off<<=1) {
    int x = (t >= off) ? sd[t-off] : 0;
    __syncthreads();
    sd[t] += x;
    __syncthreads();
  }
  if (i < n) excl[i] = sd[t] - v;
  if (t == 255) partial[blockIdx.x] = sd[255];
}
__global__ __launch_bounds__(256) void k_scan2(int* __restrict__ partial, int nb) {
  __shared__ int sd[256];
  int t = threadIdx.x;
  int v = (t < nb) ? partial[t] : 0;
  sd[t] = v; __syncthreads();
  for (int off=1; off<256; off<<=1) {
    int x = (t >= off) ? sd[t-off] : 0;
    __syncthreads();
    sd[t] += x;
    __syncthreads();
  }
  partial[t] = sd[t] - v;
}
__global__ void k_scan3(int* __restrict__ row_start, int* __restrict__ cursor,
    const int* __restrict__ partial, const int* __restrict__ count, int n) {
  int i = blockIdx.x*256 + threadIdx.x;
  if (i < n) {
    int v = row_start[i] + partial[blockIdx.x];
    row_start[i] = v;
    cursor[i] = v;
    if (i == n-1) row_start[n] = v + count[i];
  }
}
__global__ void k_fill(const int* __restrict__ ei, int* __restrict__ cursor,
    int* __restrict__ csr, int E, int n) {
  int t = blockIdx.x*256 + threadIdx.x;
  if (t < E + n) {
    int s, d;
    if (t < E) { s = ei[t]; d = ei[E+t]; } else { s = t - E; d = s; }
    int p = atomicAdd(&cursor[d], 1);
    csr[p] = s;
  }
}

// ---------------- GAT softmax + aggregate, one WAVE per dst node ----------------
// 4 nodes / 256-thread block; wave-synchronous. bf16 h rows (512B); 2 edges per
// inner iteration: lane half (lane>>5) picks edge parity, 32 lanes x 16B cover a row.
__global__ __launch_bounds__(256) void k_gat(const unsigned short* __restrict__ hbf,
    const float4* __restrict__ a_src, const float4* __restrict__ a_dst,
    const int* __restrict__ row_start, const int* __restrict__ csr,
    const float* __restrict__ bias, float* __restrict__ out_conv) {
  int w = threadIdx.x >> 6, lane = threadIdx.x & 63;
  int n = blockIdx.x * 4 + w;          // grid = N/4 exactly
  int half = lane >> 5, cl = lane & 31;
  int c0 = cl * 8;                     // this lane's 8 channels
  int hd8 = cl >> 3;                   // head owning those channels

  __shared__ float s_p[4][64][4];      // [wave][edge][head]

  float4 ad = a_dst[n];
  float m0=-INFINITY, m1=-INFINITY, m2=-INFINITY, m3=-INFINITY;
  float4 l4 = make_float4(0.f,0.f,0.f,0.f);
  float acc[8];
  #pragma unroll
  for (int k=0;k<8;k++) acc[k]=0.f;

  int beg = row_start[n];
  int deg = row_start[n+1] - beg;

  for (int cb = 0; cb < deg; cb += 64) {
    int cnt = min(64, deg - cb);
    int s = 0;
    float4 e = make_float4(-INFINITY,-INFINITY,-INFINITY,-INFINITY);
    if (lane < cnt) {
      s = csr[beg + cb + lane];
      float4 as = a_src[s];
      e.x = lrelu(as.x + ad.x);
      e.y = lrelu(as.y + ad.y);
      e.z = lrelu(as.z + ad.z);
      e.w = lrelu(as.w + ad.w);
    }
    float4 cm = e;
    #pragma unroll
    for (int d=32; d>=1; d>>=1) {
      cm.x = fmaxf(cm.x, __shfl_xor(cm.x, d));
      cm.y = fmaxf(cm.y, __shfl_xor(cm.y, d));
      cm.z = fmaxf(cm.z, __shfl_xor(cm.z, d));
      cm.w = fmaxf(cm.w, __shfl_xor(cm.w, d));
    }
    float nm0 = fmaxf(m0, cm.x), nm1 = fmaxf(m1, cm.y);
    float nm2 = fmaxf(m2, cm.z), nm3 = fmaxf(m3, cm.w);
    float sc0 = __expf(m0-nm0), sc1 = __expf(m1-nm1);
    float sc2 = __expf(m2-nm2), sc3 = __expf(m3-nm3);
    m0=nm0; m1=nm1; m2=nm2; m3=nm3;
    float sch = hd8==0 ? sc0 : hd8==1 ? sc1 : hd8==2 ? sc2 : sc3;
    #pragma unroll
    for (int k=0;k<8;k++) acc[k] *= sch;
    float4 p = make_float4(0.f,0.f,0.f,0.f);
    if (lane < cnt) {
      p.x = __expf(e.x - nm0);
      p.y = __expf(e.y - nm1);
      p.z = __expf(e.z - nm2);
      p.w = __expf(e.w - nm3);
    }
    l4.x = l4.x*sc0 + p.x;
    l4.y = l4.y*sc1 + p.y;
    l4.z = l4.z*sc2 + p.z;
    l4.w = l4.w*sc3 + p.w;
    st4(&s_p[w][lane][0], p);          // wave-local
    int pairs = (cnt + 1) >> 1;
    for (int j2 = 0; j2 < pairs; j2++) {
      int jj = 2*j2 + half;
      int sj = __shfl(s, jj & 63);
      if (jj < cnt) {
        float pw = s_p[w][jj][hd8];
        uint4 u = *(const uint4*)&hbf[(size_t)sj*HC + c0];
        acc[0] += pw*bflo(u.x); acc[1] += pw*bfhi(u.x);
        acc[2] += pw*bflo(u.y); acc[3] += pw*bfhi(u.y);
        acc[4] += pw*bflo(u.z); acc[5] += pw*bfhi(u.z);
        acc[6] += pw*bflo(u.w); acc[7] += pw*bfhi(u.w);
      }
    }
  }
  #pragma unroll
  for (int d=32; d>=1; d>>=1) {
    l4.x += __shfl_xor(l4.x, d);
    l4.y += __shfl_xor(l4.y, d);
    l4.z += __shfl_xor(l4.z, d);
    l4.w += __shfl_xor(l4.w, d);
  }
  // combine the two edge-parity halves
  #pragma unroll
  for (int k=0;k<8;k++) acc[k] += __shfl_xor(acc[k], 32);
  float lh = hd8==0 ? l4.x : hd8==1 ? l4.y : hd8==2 ? l4.z : l4.w;
  float inv = 1.f / lh;
  int kb = half * 4;                   // this lane stores 4 of the pair's 8 channels
  float4 b = ld4(&bias[c0 + kb]);
  float4 r;
  r.x = fmaxf(acc[kb+0]*inv + b.x, 0.f);
  r.y = fmaxf(acc[kb+1]*inv + b.y, 0.f);
  r.z = fmaxf(acc[kb+2]*inv + b.z, 0.f);
  r.w = fmaxf(acc[kb+3]*inv + b.w, 0.f);
  st4(&out_conv[(size_t)n*HC + c0 + kb], r);
}

// ---------------- lin1: hid = relu(X@W1 + b1)  [M,256]x[256,64] ----------------
__global__ __launch_bounds__(256) void k_lin1(const float* __restrict__ A,
    const float* __restrict__ B, const float* __restrict__ b1,
    float* __restrict__ C, int M) {
  __shared__ float As[BK][BM+4];
  __shared__ float Bs[BK][68];
  int t = threadIdx.x;
  int tx = t & 15, ty = t >> 4;
  int row0 = blockIdx.x * BM;
  float acc[4][4];
  #pragma unroll
  for (int i=0;i<4;i++)
    #pragma unroll
    for (int j=0;j<4;j++) acc[i][j]=0.f;
  int lm = t >> 2, lk = (t & 3) * 4;
  int br = t >> 4, bc = (t & 15) * 4;
  for (int kk = 0; kk < 256; kk += BK) {
    float4 av = make_float4(0.f,0.f,0.f,0.f);
    if (row0 + lm < M) av = ld4(&A[(size_t)(row0+lm)*256 + kk + lk]);
    As[lk+0][lm]=av.x; As[lk+1][lm]=av.y; As[lk+2][lm]=av.z; As[lk+3][lm]=av.w;
    st4(&Bs[br][bc], ld4(&B[(size_t)(kk+br)*64 + bc]));
    __syncthreads();
    #pragma unroll
    for (int k=0;k<BK;k++){
      float ar[4], brr[4];
      #pragma unroll
      for (int i=0;i<4;i++) ar[i]=As[k][ty*4+i];
      #pragma unroll
      for (int j=0;j<4;j++) brr[j]=Bs[k][tx*4+j];
      #pragma unroll
      for (int i=0;i<4;i++)
        #pragma unroll
        for (int j=0;j<4;j++)
          acc[i][j] += ar[i]*brr[j];
    }
    __syncthreads();
  }
  float4 bb = ld4(&b1[tx*4]);
  #pragma unroll
  for (int i=0;i<4;i++){
    int row = row0 + ty*4 + i;
    if (row < M) {
      float4 v = make_float4(fmaxf(acc[i][0]+bb.x,0.f), fmaxf(acc[i][1]+bb.y,0.f),
                             fmaxf(acc[i][2]+bb.z,0.f), fmaxf(acc[i][3]+bb.w,0.f));
      st4(&C[(size_t)row*64 + tx*4], v);
    }
  }
}

// ---------------- lin2: out = hid@W2 + b2  [M,64]x[64,40] ----------------
__global__ __launch_bounds__(256) void k_lin2(const float* __restrict__ Hd,
    const float* __restrict__ W2, const float* __restrict__ b2,
    float* __restrict__ out, int M) {
  __shared__ float Hs[64][68];
  __shared__ float W2s[64][44];
  int t = threadIdx.x;
  int rowb = blockIdx.x * 64;
  #pragma unroll
  for (int i=0;i<3;i++){
    int idx = t + 256*i;
    if (idx < 640) {
      int k = idx/10, c4 = (idx%10)*4;
      st4(&W2s[k][c4], ld4(&W2[(size_t)k*40 + c4]));
    }
  }
  #pragma unroll
  for (int i=0;i<4;i++){
    int idx = t + 256*i;
    int r = idx >> 4, c4 = (idx & 15)*4;
    float4 v = make_float4(0.f,0.f,0.f,0.f);
    if (rowb + r < M) v = ld4(&Hd[(size_t)(rowb+r)*64 + c4]);
    st4(&Hs[r][c4], v);
  }
  __syncthreads();
  int tx = t & 15, ty = t >> 4;
  if (tx < 10) {
    float acc[4][4];
    #pragma unroll
    for (int i=0;i<4;i++)
      #pragma unroll
      for (int j=0;j<4;j++) acc[i][j]=0.f;
    #pragma unroll
    for (int k4=0;k4<16;k4++){
      float4 a[4], wv[4];
      #pragma unroll
      for (int i=0;i<4;i++) a[i] = ld4(&Hs[ty*4+i][k4*4]);
      #pragma unroll
      for (int kk=0;kk<4;kk++) wv[kk] = ld4(&W2s[k4*4+kk][tx*4]);
      #pragma unroll
      for (int i=0;i<4;i++){
        acc[i][0] += a[i].x*wv[0].x + a[i].y*wv[1].x + a[i].z*wv[2].x + a[i].w*wv[3].x;
        acc[i][1] += a[i].x*wv[0].y + a[i].y*wv[1].y + a[i].z*wv[2].y + a[i].w*wv[3].y;
        acc[i][2] += a[i].x*wv[0].z + a[i].y*wv[1].z + a[i].z*wv[2].z + a[i].w*wv[3].z;
        acc[i][3] += a[i].x*wv[0].w + a[i].y*wv[1].w + a[i].z*wv[2].w + a[i].w*wv[3].w;
      }
    }
    float4 bb = ld4(&b2[tx*4]);
    #pragma unroll
    for (int i=0;i<4;i++){
      int row = rowb + ty*4 + i;
      if (row < M) {
        float4 v = make_float4(acc[i][0]+bb.x, acc[i][1]+bb.y,
                               acc[i][2]+bb.z, acc[i][3]+bb.w);
        st4(&out[(size_t)row*40 + tx*4], v);
      }
    }
  }
}

extern "C" void kernel_launch(void* const* d_in, const int* in_sizes, int n_in,
                              void* d_out, int out_size, void* d_ws, size_t ws_size,
                              hipStream_t stream) {
  const int Nn = in_sizes[0] / HC;   // 50000
  const int E  = in_sizes[1] / 2;    // 800000
  const float* x        = (const float*)d_in[0];
  const int*   ei       = (const int*)d_in[1];
  const float* W        = (const float*)d_in[2];
  const float* att_src  = (const float*)d_in[3];
  const float* att_dst  = (const float*)d_in[4];
  const float* biasconv = (const float*)d_in[5];
  const float* W1       = (const float*)d_in[6];
  const float* b1       = (const float*)d_in[7];
  const float* W2       = (const float*)d_in[8];
  const float* b2       = (const float*)d_in[9];
  float* out = (float*)d_out;

  size_t off = 0;
  auto alloc = [&](size_t bytes)->void* {
    void* p = (void*)((char*)d_ws + off);
    off += (bytes + 255) & ~(size_t)255;
    return p;
  };
  unsigned short* hbf = (unsigned short*)alloc((size_t)Nn*HC*sizeof(unsigned short));
  float* outc     = (float*)alloc((size_t)Nn*HC*sizeof(float));
  float* hid      = (float*)alloc((size_t)Nn*64*sizeof(float));
  float* a_src_v  = (float*)alloc((size_t)Nn*4*sizeof(float));
  float* a_dst_v  = (float*)alloc((size_t)Nn*4*sizeof(float));
  int*   count    = (int*)alloc((size_t)Nn*sizeof(int));
  int*   rowstart = (int*)alloc((size_t)(Nn+1)*sizeof(int));
  int*   cursor   = (int*)alloc((size_t)Nn*sizeof(int));
  int*   partial  = (int*)alloc(256*sizeof(int));
  int*   csr      = (int*)alloc((size_t)(E+Nn)*sizeof(int));
  (void)ws_size; (void)n_in; (void)out_size;

  dim3 blk(256);
  k_gemm1<<<dim3(HC/BN, (Nn+BM-1)/BM), blk, 0, stream>>>(x, W, hbf, a_src_v, a_dst_v,
                                                          att_src, att_dst, Nn);
  k_init_count<<<dim3((Nn+255)/256), blk, 0, stream>>>(count, Nn);
  k_count<<<dim3((E+255)/256), blk, 0, stream>>>(ei, count, E);
  int nb = (Nn+255)/256;
  k_scan1<<<dim3(nb), blk, 0, stream>>>(count, rowstart, partial, Nn);
  k_scan2<<<dim3(1), blk, 0, stream>>>(partial, nb);
  k_scan3<<<dim3(nb), blk, 0, stream>>>(rowstart, cursor, partial, count, Nn);
  k_fill<<<dim3((E+Nn+255)/256), blk, 0, stream>>>(ei, cursor, csr, E, Nn);
  k_gat<<<dim3(Nn/4), blk, 0, stream>>>(hbf, (const float4*)a_src_v, (const float4*)a_dst_v,
                                        rowstart, csr, biasconv, outc);
  k_lin1<<<dim3((Nn+BM-1)/BM), blk, 0, stream>>>(outc, W1, b1, hid, Nn);
  k_lin2<<<dim3((Nn+63)/64), blk, 0, stream>>>(hid, W2, b2, out, Nn);
}

// Round 4
// 409.893 us; speedup vs baseline: 1.3385x; 1.0463x over previous
//
#include <hip/hip_runtime.h>
#include <math.h>

#define HEADS 4
#define CH 64
#define HC 256          // HEADS*CH
#define SLOPE 0.2f

typedef __attribute__((ext_vector_type(8))) short bf16x8;
typedef __attribute__((ext_vector_type(4))) float f32x4;

__device__ __forceinline__ float4 ld4(const float* p){ return *(const float4*)p; }
__device__ __forceinline__ void st4(float* p, float4 v){ *(float4*)p = v; }
__device__ __forceinline__ float lrelu(float x){ return x > 0.f ? x : SLOPE * x; }
__device__ __forceinline__ unsigned short f2bf(float f){
  union { float f; unsigned int u; } v; v.f = f;
  unsigned int r = v.u + 0x7fffu + ((v.u >> 16) & 1u);   // RNE
  return (unsigned short)(r >> 16);
}
__device__ __forceinline__ float bflo(unsigned int u){
  union { unsigned int u; float f; } v; v.u = u << 16; return v.f;
}
__device__ __forceinline__ float bfhi(unsigned int u){
  union { unsigned int u; float f; } v; v.u = u & 0xffff0000u; return v.f;
}

// ---------------- split W into bf16 hi/lo, transposed to [N][K] ----------------
__global__ __launch_bounds__(256) void k_splitB(const float* __restrict__ W,
    unsigned short* __restrict__ hi, unsigned short* __restrict__ lo) {
  int n = blockIdx.x, k = threadIdx.x;
  float v = W[(size_t)k*256 + n];
  unsigned int u = __float_as_uint(v);
  hi[(size_t)n*256 + k] = (unsigned short)(u >> 16);
  float hf = __uint_as_float(u & 0xffff0000u);
  lo[(size_t)n*256 + k] = (unsigned short)(__float_as_uint(v - hf) >> 16);
}

// ---------------- GEMM1: hbf = bf16(x @ W) via 3-pass split-bf16 MFMA ----------------
// grid (2 colTiles, 391 rowTiles), 128x128 tile, BK=64.
// A staged in LDS (XOR-swizzled 8-elem groups); B frags read direct from L2 (B_t pre-split).
__global__ __launch_bounds__(256) void k_gemm1(const float* __restrict__ A,
    const unsigned short* __restrict__ Bhi_t, const unsigned short* __restrict__ Blo_t,
    unsigned short* __restrict__ hbf, int M) {
  __shared__ unsigned short Ahi[128*64];
  __shared__ unsigned short Alo[128*64];
  int t = threadIdx.x;
  int lane = t & 63, w = t >> 6;
  int wr = w >> 1, wc = w & 1;
  int ln15 = lane & 15, lq = lane >> 4;
  int row0 = blockIdx.y * 128, col0 = blockIdx.x * 128;
  f32x4 acc[4][4];
  #pragma unroll
  for (int i=0;i<4;i++)
    #pragma unroll
    for (int j=0;j<4;j++) acc[i][j] = (f32x4){0.f,0.f,0.f,0.f};

  for (int kk = 0; kk < 256; kk += 64) {
    // ---- stage A chunk (128 rows x 64 k) as hi/lo bf16, XOR-swizzled ----
    #pragma unroll
    for (int i = 0; i < 8; i++) {
      int f = t + 256*i;
      int r = f >> 4, kq = f & 15;         // kq indexes float4 within the 64-k chunk
      float4 v = make_float4(0.f,0.f,0.f,0.f);
      if (row0 + r < M) v = ld4(&A[(size_t)(row0+r)*256 + kk + kq*4]);
      unsigned int ux = __float_as_uint(v.x), uy = __float_as_uint(v.y);
      unsigned int uz = __float_as_uint(v.z), uw = __float_as_uint(v.w);
      unsigned int hp0 = (ux >> 16) | (uy & 0xffff0000u);
      unsigned int hp1 = (uz >> 16) | (uw & 0xffff0000u);
      float lx = v.x - __uint_as_float(ux & 0xffff0000u);
      float ly = v.y - __uint_as_float(uy & 0xffff0000u);
      float lz = v.z - __uint_as_float(uz & 0xffff0000u);
      float lw = v.w - __uint_as_float(uw & 0xffff0000u);
      unsigned int lp0 = (__float_as_uint(lx) >> 16) | (__float_as_uint(ly) & 0xffff0000u);
      unsigned int lp1 = (__float_as_uint(lz) >> 16) | (__float_as_uint(lw) & 0xffff0000u);
      int q = kq >> 1, hf = kq & 1;
      int off = r*64 + ((q ^ (r & 7)) << 3) + (hf << 2);
      *(uint2*)&Ahi[off] = make_uint2(hp0, hp1);
      *(uint2*)&Alo[off] = make_uint2(lp0, lp1);
    }
    __syncthreads();
    #pragma unroll
    for (int ks = 0; ks < 2; ks++) {
      bf16x8 ah[4], al[4], bh[4], bl[4];
      #pragma unroll
      for (int i = 0; i < 4; i++) {
        int r = wr*64 + i*16 + ln15;
        int q = ks*4 + lq;
        int off = r*64 + ((q ^ (r & 7)) << 3);
        ah[i] = *(bf16x8*)&Ahi[off];
        al[i] = *(bf16x8*)&Alo[off];
      }
      #pragma unroll
      for (int j = 0; j < 4; j++) {
        int n = col0 + wc*64 + j*16 + ln15;
        int k = kk + ks*32 + lq*8;
        bh[j] = *(const bf16x8*)&Bhi_t[(size_t)n*256 + k];
        bl[j] = *(const bf16x8*)&Blo_t[(size_t)n*256 + k];
      }
      #pragma unroll
      for (int i = 0; i < 4; i++)
        #pragma unroll
        for (int j = 0; j < 4; j++) {
          acc[i][j] = __builtin_amdgcn_mfma_f32_16x16x32_bf16(ah[i], bh[j], acc[i][j], 0,0,0);
          acc[i][j] = __builtin_amdgcn_mfma_f32_16x16x32_bf16(al[i], bh[j], acc[i][j], 0,0,0);
          acc[i][j] = __builtin_amdgcn_mfma_f32_16x16x32_bf16(ah[i], bl[j], acc[i][j], 0,0,0);
        }
    }
    __syncthreads();
  }
  // ---- epilogue: C/D layout col=lane&15, row=(lane>>4)*4+reg ----
  #pragma unroll
  for (int i = 0; i < 4; i++) {
    #pragma unroll
    for (int r = 0; r < 4; r++) {
      int row = row0 + wr*64 + i*16 + lq*4 + r;
      if (row < M) {
        #pragma unroll
        for (int j = 0; j < 4; j++) {
          int col = col0 + wc*64 + j*16 + ln15;
          hbf[(size_t)row*HC + col] = f2bf(acc[i][j][r]);
        }
      }
    }
  }
}

// ---------------- attention coefficients from bf16 h: a_src/a_dst [N,4] ----------------
__global__ __launch_bounds__(256) void k_attn(const unsigned short* __restrict__ hbf,
    const float* __restrict__ att_src, const float* __restrict__ att_dst,
    float* __restrict__ a_src, float* __restrict__ a_dst, int n) {
  int gid = blockIdx.x*256 + threadIdx.x;
  int node = gid >> 5;
  int sl = gid & 31;
  if (node >= n) return;
  int c0 = sl*8, head = sl >> 3;
  uint4 u = *(const uint4*)&hbf[(size_t)node*HC + c0];
  float v0 = bflo(u.x), v1 = bfhi(u.x), v2 = bflo(u.y), v3 = bfhi(u.y);
  float v4 = bflo(u.z), v5 = bfhi(u.z), v6 = bflo(u.w), v7 = bfhi(u.w);
  const float* as = &att_src[head*CH + (sl&7)*8];
  const float* ad = &att_dst[head*CH + (sl&7)*8];
  float4 a0 = ld4(as), a1 = ld4(as+4);
  float4 d0 = ld4(ad), d1 = ld4(ad+4);
  float ps = v0*a0.x + v1*a0.y + v2*a0.z + v3*a0.w
           + v4*a1.x + v5*a1.y + v6*a1.z + v7*a1.w;
  float pd = v0*d0.x + v1*d0.y + v2*d0.z + v3*d0.w
           + v4*d1.x + v5*d1.y + v6*d1.z + v7*d1.w;
  #pragma unroll
  for (int m=4; m>=1; m>>=1) { ps += __shfl_xor(ps, m); pd += __shfl_xor(pd, m); }
  if ((sl & 7) == 0) { a_src[node*4+head] = ps; a_dst[node*4+head] = pd; }
}

// ---------------- CSR build ----------------
__global__ void k_init_count(int* __restrict__ count, int n) {
  int i = blockIdx.x*256 + threadIdx.x;
  if (i < n) count[i] = 1;               // self-loop
}
__global__ void k_count(const int* __restrict__ ei, int* __restrict__ count, int E) {
  int e = blockIdx.x*256 + threadIdx.x;
  if (e < E) atomicAdd(&count[ei[E+e]], 1);
}
__global__ __launch_bounds__(256) void k_scan1(const int* __restrict__ count,
    int* __restrict__ excl, int* __restrict__ partial, int n) {
  __shared__ int sd[256];
  int t = threadIdx.x, i = blockIdx.x*256 + t;
  int v = (i < n) ? count[i] : 0;
  sd[t] = v; __syncthreads();
  for (int off=1; off<256; off<<=1) {
    int x = (t >= off) ? sd[t-off] : 0;
    __syncthreads();
    sd[t] += x;
    __syncthreads();
  }
  if (i < n) excl[i] = sd[t] - v;
  if (t == 255) partial[blockIdx.x] = sd[255];
}
__global__ __launch_bounds__(256) void k_scan2(int* __restrict__ partial, int nb) {
  __shared__ int sd[256];
  int t = threadIdx.x;
  int v = (t < nb) ? partial[t] : 0;
  sd[t] = v; __syncthreads();
  for (int off=1; off<256; off<<=1) {
    int x = (t >= off) ? sd[t-off] : 0;
    __syncthreads();
    sd[t] += x;
    __syncthreads();
  }
  partial[t] = sd[t] - v;
}
__global__ void k_scan3(int* __restrict__ row_start, int* __restrict__ cursor,
    const int* __restrict__ partial, const int* __restrict__ count, int n) {
  int i = blockIdx.x*256 + threadIdx.x;
  if (i < n) {
    int v = row_start[i] + partial[blockIdx.x];
    row_start[i] = v;
    cursor[i] = v;
    if (i == n-1) row_start[n] = v + count[i];
  }
}
__global__ void k_fill(const int* __restrict__ ei, int* __restrict__ cursor,
    int* __restrict__ csr, int E, int n) {
  int t = blockIdx.x*256 + threadIdx.x;
  if (t < E + n) {
    int s, d;
    if (t < E) { s = ei[t]; d = ei[E+t]; } else { s = t - E; d = s; }
    int p = atomicAdd(&cursor[d], 1);
    csr[p] = s;
  }
}

// ---------------- GAT softmax + aggregate, one WAVE per dst node ----------------
__global__ __launch_bounds__(256) void k_gat(const unsigned short* __restrict__ hbf,
    const float4* __restrict__ a_src, const float4* __restrict__ a_dst,
    const int* __restrict__ row_start, const int* __restrict__ csr,
    const float* __restrict__ bias, float* __restrict__ out_conv) {
  int w = threadIdx.x >> 6, lane = threadIdx.x & 63;
  int n = blockIdx.x * 4 + w;          // grid = N/4 exactly
  int half = lane >> 5, cl = lane & 31;
  int c0 = cl * 8;                     // this lane's 8 channels
  int hd8 = cl >> 3;                   // head owning those channels

  __shared__ float s_p[4][64][4];      // [wave][edge][head]

  float4 ad = a_dst[n];
  float m0=-INFINITY, m1=-INFINITY, m2=-INFINITY, m3=-INFINITY;
  float4 l4 = make_float4(0.f,0.f,0.f,0.f);
  float acc[8];
  #pragma unroll
  for (int k=0;k<8;k++) acc[k]=0.f;

  int beg = row_start[n];
  int deg = row_start[n+1] - beg;

  for (int cb = 0; cb < deg; cb += 64) {
    int cnt = min(64, deg - cb);
    int s = 0;
    float4 e = make_float4(-INFINITY,-INFINITY,-INFINITY,-INFINITY);
    if (lane < cnt) {
      s = csr[beg + cb + lane];
      float4 as = a_src[s];
      e.x = lrelu(as.x + ad.x);
      e.y = lrelu(as.y + ad.y);
      e.z = lrelu(as.z + ad.z);
      e.w = lrelu(as.w + ad.w);
    }
    float4 cm = e;
    #pragma unroll
    for (int d=32; d>=1; d>>=1) {
      cm.x = fmaxf(cm.x, __shfl_xor(cm.x, d));
      cm.y = fmaxf(cm.y, __shfl_xor(cm.y, d));
      cm.z = fmaxf(cm.z, __shfl_xor(cm.z, d));
      cm.w = fmaxf(cm.w, __shfl_xor(cm.w, d));
    }
    float nm0 = fmaxf(m0, cm.x), nm1 = fmaxf(m1, cm.y);
    float nm2 = fmaxf(m2, cm.z), nm3 = fmaxf(m3, cm.w);
    float sc0 = __expf(m0-nm0), sc1 = __expf(m1-nm1);
    float sc2 = __expf(m2-nm2), sc3 = __expf(m3-nm3);
    m0=nm0; m1=nm1; m2=nm2; m3=nm3;
    float sch = hd8==0 ? sc0 : hd8==1 ? sc1 : hd8==2 ? sc2 : sc3;
    #pragma unroll
    for (int k=0;k<8;k++) acc[k] *= sch;
    float4 p = make_float4(0.f,0.f,0.f,0.f);
    if (lane < cnt) {
      p.x = __expf(e.x - nm0);
      p.y = __expf(e.y - nm1);
      p.z = __expf(e.z - nm2);
      p.w = __expf(e.w - nm3);
    }
    l4.x = l4.x*sc0 + p.x;
    l4.y = l4.y*sc1 + p.y;
    l4.z = l4.z*sc2 + p.z;
    l4.w = l4.w*sc3 + p.w;
    st4(&s_p[w][lane][0], p);          // wave-local
    int pairs = (cnt + 1) >> 1;
    for (int j2 = 0; j2 < pairs; j2++) {
      int jj = 2*j2 + half;
      int sj = __shfl(s, jj & 63);
      if (jj < cnt) {
        float pw = s_p[w][jj][hd8];
        uint4 u = *(const uint4*)&hbf[(size_t)sj*HC + c0];
        acc[0] += pw*bflo(u.x); acc[1] += pw*bfhi(u.x);
        acc[2] += pw*bflo(u.y); acc[3] += pw*bfhi(u.y);
        acc[4] += pw*bflo(u.z); acc[5] += pw*bfhi(u.z);
        acc[6] += pw*bflo(u.w); acc[7] += pw*bfhi(u.w);
      }
    }
  }
  #pragma unroll
  for (int d=32; d>=1; d>>=1) {
    l4.x += __shfl_xor(l4.x, d);
    l4.y += __shfl_xor(l4.y, d);
    l4.z += __shfl_xor(l4.z, d);
    l4.w += __shfl_xor(l4.w, d);
  }
  #pragma unroll
  for (int k=0;k<8;k++) acc[k] += __shfl_xor(acc[k], 32);
  float lh = hd8==0 ? l4.x : hd8==1 ? l4.y : hd8==2 ? l4.z : l4.w;
  float inv = 1.f / lh;
  int kb = half * 4;
  float4 b = ld4(&bias[c0 + kb]);
  float4 r;
  r.x = fmaxf(acc[kb+0]*inv + b.x, 0.f);
  r.y = fmaxf(acc[kb+1]*inv + b.y, 0.f);
  r.z = fmaxf(acc[kb+2]*inv + b.z, 0.f);
  r.w = fmaxf(acc[kb+3]*inv + b.w, 0.f);
  st4(&out_conv[(size_t)n*HC + c0 + kb], r);
}

// ---------------- lin1: hid = relu(X@W1 + b1)  [M,256]x[256,64] ----------------
#define BM 64
#define BK 16
__global__ __launch_bounds__(256) void k_lin1(const float* __restrict__ A,
    const float* __restrict__ B, const float* __restrict__ b1,
    float* __restrict__ C, int M) {
  __shared__ float As[BK][BM+4];
  __shared__ float Bs[BK][68];
  int t = threadIdx.x;
  int tx = t & 15, ty = t >> 4;
  int row0 = blockIdx.x * BM;
  float acc[4][4];
  #pragma unroll
  for (int i=0;i<4;i++)
    #pragma unroll
    for (int j=0;j<4;j++) acc[i][j]=0.f;
  int lm = t >> 2, lk = (t & 3) * 4;
  int br = t >> 4, bc = (t & 15) * 4;
  for (int kk = 0; kk < 256; kk += BK) {
    float4 av = make_float4(0.f,0.f,0.f,0.f);
    if (row0 + lm < M) av = ld4(&A[(size_t)(row0+lm)*256 + kk + lk]);
    As[lk+0][lm]=av.x; As[lk+1][lm]=av.y; As[lk+2][lm]=av.z; As[lk+3][lm]=av.w;
    st4(&Bs[br][bc], ld4(&B[(size_t)(kk+br)*64 + bc]));
    __syncthreads();
    #pragma unroll
    for (int k=0;k<BK;k++){
      float ar[4], brr[4];
      #pragma unroll
      for (int i=0;i<4;i++) ar[i]=As[k][ty*4+i];
      #pragma unroll
      for (int j=0;j<4;j++) brr[j]=Bs[k][tx*4+j];
      #pragma unroll
      for (int i=0;i<4;i++)
        #pragma unroll
        for (int j=0;j<4;j++)
          acc[i][j] += ar[i]*brr[j];
    }
    __syncthreads();
  }
  float4 bb = ld4(&b1[tx*4]);
  #pragma unroll
  for (int i=0;i<4;i++){
    int row = row0 + ty*4 + i;
    if (row < M) {
      float4 v = make_float4(fmaxf(acc[i][0]+bb.x,0.f), fmaxf(acc[i][1]+bb.y,0.f),
                             fmaxf(acc[i][2]+bb.z,0.f), fmaxf(acc[i][3]+bb.w,0.f));
      st4(&C[(size_t)row*64 + tx*4], v);
    }
  }
}

// ---------------- lin2: out = hid@W2 + b2  [M,64]x[64,40] ----------------
__global__ __launch_bounds__(256) void k_lin2(const float* __restrict__ Hd,
    const float* __restrict__ W2, const float* __restrict__ b2,
    float* __restrict__ out, int M) {
  __shared__ float Hs[64][68];
  __shared__ float W2s[64][44];
  int t = threadIdx.x;
  int rowb = blockIdx.x * 64;
  #pragma unroll
  for (int i=0;i<3;i++){
    int idx = t + 256*i;
    if (idx < 640) {
      int k = idx/10, c4 = (idx%10)*4;
      st4(&W2s[k][c4], ld4(&W2[(size_t)k*40 + c4]));
    }
  }
  #pragma unroll
  for (int i=0;i<4;i++){
    int idx = t + 256*i;
    int r = idx >> 4, c4 = (idx & 15)*4;
    float4 v = make_float4(0.f,0.f,0.f,0.f);
    if (rowb + r < M) v = ld4(&Hd[(size_t)(rowb+r)*64 + c4]);
    st4(&Hs[r][c4], v);
  }
  __syncthreads();
  int tx = t & 15, ty = t >> 4;
  if (tx < 10) {
    float acc[4][4];
    #pragma unroll
    for (int i=0;i<4;i++)
      #pragma unroll
      for (int j=0;j<4;j++) acc[i][j]=0.f;
    #pragma unroll
    for (int k4=0;k4<16;k4++){
      float4 a[4], wv[4];
      #pragma unroll
      for (int i=0;i<4;i++) a[i] = ld4(&Hs[ty*4+i][k4*4]);
      #pragma unroll
      for (int kk=0;kk<4;kk++) wv[kk] = ld4(&W2s[k4*4+kk][tx*4]);
      #pragma unroll
      for (int i=0;i<4;i++){
        acc[i][0] += a[i].x*wv[0].x + a[i].y*wv[1].x + a[i].z*wv[2].x + a[i].w*wv[3].x;
        acc[i][1] += a[i].x*wv[0].y + a[i].y*wv[1].y + a[i].z*wv[2].y + a[i].w*wv[3].y;
        acc[i][2] += a[i].x*wv[0].z + a[i].y*wv[1].z + a[i].z*wv[2].z + a[i].w*wv[3].z;
        acc[i][3] += a[i].x*wv[0].w + a[i].y*wv[1].w + a[i].z*wv[2].w + a[i].w*wv[3].w;
      }
    }
    float4 bb = ld4(&b2[tx*4]);
    #pragma unroll
    for (int i=0;i<4;i++){
      int row = rowb + ty*4 + i;
      if (row < M) {
        float4 v = make_float4(acc[i][0]+bb.x, acc[i][1]+bb.y,
                               acc[i][2]+bb.z, acc[i][3]+bb.w);
        st4(&out[(size_t)row*40 + tx*4], v);
      }
    }
  }
}

extern "C" void kernel_launch(void* const* d_in, const int* in_sizes, int n_in,
                              void* d_out, int out_size, void* d_ws, size_t ws_size,
                              hipStream_t stream) {
  const int Nn = in_sizes[0] / HC;   // 50000
  const int E  = in_sizes[1] / 2;    // 800000
  const float* x        = (const float*)d_in[0];
  const int*   ei       = (const int*)d_in[1];
  const float* W        = (const float*)d_in[2];
  const float* att_src  = (const float*)d_in[3];
  const float* att_dst  = (const float*)d_in[4];
  const float* biasconv = (const float*)d_in[5];
  const float* W1       = (const float*)d_in[6];
  const float* b1       = (const float*)d_in[7];
  const float* W2       = (const float*)d_in[8];
  const float* b2       = (const float*)d_in[9];
  float* out = (float*)d_out;

  size_t off = 0;
  auto alloc = [&](size_t bytes)->void* {
    void* p = (void*)((char*)d_ws + off);
    off += (bytes + 255) & ~(size_t)255;
    return p;
  };
  unsigned short* hbf = (unsigned short*)alloc((size_t)Nn*HC*sizeof(unsigned short));
  unsigned short* Bhi = (unsigned short*)alloc((size_t)256*256*sizeof(unsigned short));
  unsigned short* Blo = (unsigned short*)alloc((size_t)256*256*sizeof(unsigned short));
  float* outc     = (float*)alloc((size_t)Nn*HC*sizeof(float));
  float* hid      = (float*)alloc((size_t)Nn*64*sizeof(float));
  float* a_src_v  = (float*)alloc((size_t)Nn*4*sizeof(float));
  float* a_dst_v  = (float*)alloc((size_t)Nn*4*sizeof(float));
  int*   count    = (int*)alloc((size_t)Nn*sizeof(int));
  int*   rowstart = (int*)alloc((size_t)(Nn+1)*sizeof(int));
  int*   cursor   = (int*)alloc((size_t)Nn*sizeof(int));
  int*   partial  = (int*)alloc(256*sizeof(int));
  int*   csr      = (int*)alloc((size_t)(E+Nn)*sizeof(int));
  (void)ws_size; (void)n_in; (void)out_size;

  dim3 blk(256);
  k_splitB<<<dim3(256), blk, 0, stream>>>(W, Bhi, Blo);
  k_gemm1<<<dim3(2, (Nn+127)/128), blk, 0, stream>>>(x, Bhi, Blo, hbf, Nn);
  k_attn<<<dim3((Nn*32+255)/256), blk, 0, stream>>>(hbf, att_src, att_dst, a_src_v, a_dst_v, Nn);
  k_init_count<<<dim3((Nn+255)/256), blk, 0, stream>>>(count, Nn);
  k_count<<<dim3((E+255)/256), blk, 0, stream>>>(ei, count, E);
  int nb = (Nn+255)/256;
  k_scan1<<<dim3(nb), blk, 0, stream>>>(count, rowstart, partial, Nn);
  k_scan2<<<dim3(1), blk, 0, stream>>>(partial, nb);
  k_scan3<<<dim3(nb), blk, 0, stream>>>(rowstart, cursor, partial, count, Nn);
  k_fill<<<dim3((E+Nn+255)/256), blk, 0, stream>>>(ei, cursor, csr, E, Nn);
  k_gat<<<dim3(Nn/4), blk, 0, stream>>>(hbf, (const float4*)a_src_v, (const float4*)a_dst_v,
                                        rowstart, csr, biasconv, outc);
  k_lin1<<<dim3((Nn+BM-1)/BM), blk, 0, stream>>>(outc, W1, b1, hid, Nn);
  k_lin2<<<dim3((Nn+63)/64), blk, 0, stream>>>(hid, W2, b2, out, Nn);
}

// Round 5
// 392.579 us; speedup vs baseline: 1.3975x; 1.0441x over previous
//
#include <hip/hip_runtime.h>
#include <math.h>

#define HEADS 4
#define CH 64
#define HC 256          // HEADS*CH
#define SLOPE 0.2f

typedef __attribute__((ext_vector_type(8))) short bf16x8;
typedef __attribute__((ext_vector_type(4))) float f32x4;

__device__ __forceinline__ float4 ld4(const float* p){ return *(const float4*)p; }
__device__ __forceinline__ void st4(float* p, float4 v){ *(float4*)p = v; }
__device__ __forceinline__ float lrelu(float x){ return x > 0.f ? x : SLOPE * x; }
__device__ __forceinline__ unsigned short f2bf(float f){
  union { float f; unsigned int u; } v; v.f = f;
  unsigned int r = v.u + 0x7fffu + ((v.u >> 16) & 1u);   // RNE
  return (unsigned short)(r >> 16);
}
__device__ __forceinline__ float bflo(unsigned int u){
  union { unsigned int u; float f; } v; v.u = u << 16; return v.f;
}
__device__ __forceinline__ float bfhi(unsigned int u){
  union { unsigned int u; float f; } v; v.u = u & 0xffff0000u; return v.f;
}

// ---------------- split W into bf16 hi/lo, transposed to [N][K] ----------------
__global__ __launch_bounds__(256) void k_splitB(const float* __restrict__ W,
    unsigned short* __restrict__ hi, unsigned short* __restrict__ lo) {
  int n = blockIdx.x, k = threadIdx.x;
  float v = W[(size_t)k*256 + n];
  unsigned int u = __float_as_uint(v);
  hi[(size_t)n*256 + k] = (unsigned short)(u >> 16);
  float hf = __uint_as_float(u & 0xffff0000u);
  lo[(size_t)n*256 + k] = (unsigned short)(__float_as_uint(v - hf) >> 16);
}

// ---------------- GEMM1: hbf = bf16(x @ W) via 3-pass split-bf16 MFMA ----------------
// 128x128 tile, BK=64; A and B both staged in LDS (XOR swizzle, zero conflicts);
// next-K global loads prefetched into registers during the MFMA section.
__global__ __launch_bounds__(256) void k_gemm1(const float* __restrict__ A,
    const unsigned short* __restrict__ Bhi_t, const unsigned short* __restrict__ Blo_t,
    unsigned short* __restrict__ hbf, int M) {
  __shared__ unsigned short Ahi[128*64];
  __shared__ unsigned short Alo[128*64];
  __shared__ unsigned short Bhi[128*64];
  __shared__ unsigned short Blo[128*64];
  int t = threadIdx.x;
  int lane = t & 63, w = t >> 6;
  int wr = w >> 1, wc = w & 1;
  int ln15 = lane & 15, lq = lane >> 4;
  int row0 = blockIdx.y * 128, col0 = blockIdx.x * 128;
  f32x4 acc[4][4];
  #pragma unroll
  for (int i=0;i<4;i++)
    #pragma unroll
    for (int j=0;j<4;j++) acc[i][j] = (f32x4){0.f,0.f,0.f,0.f};

  float4 areg[8];
  uint4  bhreg[4], blreg[4];

  auto loadG = [&](int kk){
    #pragma unroll
    for (int i = 0; i < 8; i++) {
      int f = t + 256*i;
      int r = f >> 4, kq = f & 15;
      areg[i] = (row0 + r < M) ? ld4(&A[(size_t)(row0+r)*256 + kk + kq*4])
                               : make_float4(0.f,0.f,0.f,0.f);
    }
    #pragma unroll
    for (int i = 0; i < 4; i++) {
      int f = t + 256*i;
      int n = f >> 3, q = f & 7;
      size_t g = (size_t)(col0+n)*256 + kk + q*8;
      bhreg[i] = *(const uint4*)&Bhi_t[g];
      blreg[i] = *(const uint4*)&Blo_t[g];
    }
  };
  auto stageLDS = [&](){
    #pragma unroll
    for (int i = 0; i < 8; i++) {
      int f = t + 256*i;
      int r = f >> 4, kq = f & 15;
      float4 v = areg[i];
      unsigned int ux = __float_as_uint(v.x), uy = __float_as_uint(v.y);
      unsigned int uz = __float_as_uint(v.z), uw = __float_as_uint(v.w);
      unsigned int hp0 = (ux >> 16) | (uy & 0xffff0000u);
      unsigned int hp1 = (uz >> 16) | (uw & 0xffff0000u);
      float lx = v.x - __uint_as_float(ux & 0xffff0000u);
      float ly = v.y - __uint_as_float(uy & 0xffff0000u);
      float lz = v.z - __uint_as_float(uz & 0xffff0000u);
      float lw = v.w - __uint_as_float(uw & 0xffff0000u);
      unsigned int lp0 = (__float_as_uint(lx) >> 16) | (__float_as_uint(ly) & 0xffff0000u);
      unsigned int lp1 = (__float_as_uint(lz) >> 16) | (__float_as_uint(lw) & 0xffff0000u);
      int q = kq >> 1, hf = kq & 1;
      int off = r*64 + ((q ^ (r & 7)) << 3) + (hf << 2);
      *(uint2*)&Ahi[off] = make_uint2(hp0, hp1);
      *(uint2*)&Alo[off] = make_uint2(lp0, lp1);
    }
    #pragma unroll
    for (int i = 0; i < 4; i++) {
      int f = t + 256*i;
      int n = f >> 3, q = f & 7;
      int off = n*64 + ((q ^ (n & 7)) << 3);
      *(uint4*)&Bhi[off] = bhreg[i];
      *(uint4*)&Blo[off] = blreg[i];
    }
  };

  loadG(0);
  for (int kk = 0; kk < 256; kk += 64) {
    stageLDS();
    __syncthreads();
    if (kk < 192) loadG(kk + 64);      // prefetch next chunk while MFMAs run
    #pragma unroll
    for (int ks = 0; ks < 2; ks++) {
      int q = ks*4 + lq;
      bf16x8 bh[4], bl[4];
      #pragma unroll
      for (int j = 0; j < 4; j++) {
        int n = wc*64 + j*16 + ln15;
        int off = n*64 + ((q ^ (n & 7)) << 3);
        bh[j] = *(bf16x8*)&Bhi[off];
        bl[j] = *(bf16x8*)&Blo[off];
      }
      #pragma unroll
      for (int i = 0; i < 4; i++) {
        int r = wr*64 + i*16 + ln15;
        int off = r*64 + ((q ^ (r & 7)) << 3);
        bf16x8 ah = *(bf16x8*)&Ahi[off];
        bf16x8 al = *(bf16x8*)&Alo[off];
        #pragma unroll
        for (int j = 0; j < 4; j++) {
          acc[i][j] = __builtin_amdgcn_mfma_f32_16x16x32_bf16(ah, bh[j], acc[i][j], 0,0,0);
          acc[i][j] = __builtin_amdgcn_mfma_f32_16x16x32_bf16(al, bh[j], acc[i][j], 0,0,0);
          acc[i][j] = __builtin_amdgcn_mfma_f32_16x16x32_bf16(ah, bl[j], acc[i][j], 0,0,0);
        }
      }
    }
    __syncthreads();
  }
  // ---- epilogue: C/D layout col=lane&15, row=(lane>>4)*4+reg ----
  #pragma unroll
  for (int i = 0; i < 4; i++) {
    #pragma unroll
    for (int r = 0; r < 4; r++) {
      int row = row0 + wr*64 + i*16 + lq*4 + r;
      if (row < M) {
        #pragma unroll
        for (int j = 0; j < 4; j++) {
          int col = col0 + wc*64 + j*16 + ln15;
          hbf[(size_t)row*HC + col] = f2bf(acc[i][j][r]);
        }
      }
    }
  }
}

// ---------------- attention coefficients from bf16 h: a_src/a_dst [N,4] ----------------
__global__ __launch_bounds__(256) void k_attn(const unsigned short* __restrict__ hbf,
    const float* __restrict__ att_src, const float* __restrict__ att_dst,
    float* __restrict__ a_src, float* __restrict__ a_dst, int n) {
  int gid = blockIdx.x*256 + threadIdx.x;
  int node = gid >> 5;
  int sl = gid & 31;
  if (node >= n) return;
  int c0 = sl*8, head = sl >> 3;
  uint4 u = *(const uint4*)&hbf[(size_t)node*HC + c0];
  float v0 = bflo(u.x), v1 = bfhi(u.x), v2 = bflo(u.y), v3 = bfhi(u.y);
  float v4 = bflo(u.z), v5 = bfhi(u.z), v6 = bflo(u.w), v7 = bfhi(u.w);
  const float* as = &att_src[head*CH + (sl&7)*8];
  const float* ad = &att_dst[head*CH + (sl&7)*8];
  float4 a0 = ld4(as), a1 = ld4(as+4);
  float4 d0 = ld4(ad), d1 = ld4(ad+4);
  float ps = v0*a0.x + v1*a0.y + v2*a0.z + v3*a0.w
           + v4*a1.x + v5*a1.y + v6*a1.z + v7*a1.w;
  float pd = v0*d0.x + v1*d0.y + v2*d0.z + v3*d0.w
           + v4*d1.x + v5*d1.y + v6*d1.z + v7*d1.w;
  #pragma unroll
  for (int m=4; m>=1; m>>=1) { ps += __shfl_xor(ps, m); pd += __shfl_xor(pd, m); }
  if ((sl & 7) == 0) { a_src[node*4+head] = ps; a_dst[node*4+head] = pd; }
}

// ---------------- CSR build ----------------
__global__ void k_init_count(int* __restrict__ count, int n) {
  int i = blockIdx.x*256 + threadIdx.x;
  if (i < n) count[i] = 1;               // self-loop
}
__global__ void k_count(const int* __restrict__ ei, int* __restrict__ count, int E) {
  int e = blockIdx.x*256 + threadIdx.x;
  if (e < E) atomicAdd(&count[ei[E+e]], 1);
}
__global__ __launch_bounds__(256) void k_scan1(const int* __restrict__ count,
    int* __restrict__ excl, int* __restrict__ partial, int n) {
  __shared__ int sd[256];
  int t = threadIdx.x, i = blockIdx.x*256 + t;
  int v = (i < n) ? count[i] : 0;
  sd[t] = v; __syncthreads();
  for (int off=1; off<256; off<<=1) {
    int x = (t >= off) ? sd[t-off] : 0;
    __syncthreads();
    sd[t] += x;
    __syncthreads();
  }
  if (i < n) excl[i] = sd[t] - v;
  if (t == 255) partial[blockIdx.x] = sd[255];
}
__global__ __launch_bounds__(256) void k_scan2(int* __restrict__ partial, int nb) {
  __shared__ int sd[256];
  int t = threadIdx.x;
  int v = (t < nb) ? partial[t] : 0;
  sd[t] = v; __syncthreads();
  for (int off=1; off<256; off<<=1) {
    int x = (t >= off) ? sd[t-off] : 0;
    __syncthreads();
    sd[t] += x;
    __syncthreads();
  }
  partial[t] = sd[t] - v;
}
__global__ void k_scan3(int* __restrict__ row_start, int* __restrict__ cursor,
    const int* __restrict__ partial, const int* __restrict__ count, int n) {
  int i = blockIdx.x*256 + threadIdx.x;
  if (i < n) {
    int v = row_start[i] + partial[blockIdx.x];
    row_start[i] = v;
    cursor[i] = v;
    if (i == n-1) row_start[n] = v + count[i];
  }
}
__global__ void k_fill(const int* __restrict__ ei, int* __restrict__ cursor,
    int* __restrict__ csr, int E, int n) {
  int t = blockIdx.x*256 + threadIdx.x;
  if (t < E + n) {
    int s, d;
    if (t < E) { s = ei[t]; d = ei[E+t]; } else { s = t - E; d = s; }
    int p = atomicAdd(&cursor[d], 1);
    csr[p] = s;
  }
}

// ---------------- GAT softmax + aggregate, one WAVE per dst node ----------------
__global__ __launch_bounds__(256) void k_gat(const unsigned short* __restrict__ hbf,
    const float4* __restrict__ a_src, const float4* __restrict__ a_dst,
    const int* __restrict__ row_start, const int* __restrict__ csr,
    const float* __restrict__ bias, float* __restrict__ out_conv) {
  int w = threadIdx.x >> 6, lane = threadIdx.x & 63;
  int n = blockIdx.x * 4 + w;          // grid = N/4 exactly
  int half = lane >> 5, cl = lane & 31;
  int c0 = cl * 8;                     // this lane's 8 channels
  int hd8 = cl >> 3;                   // head owning those channels

  __shared__ float s_p[4][64][4];      // [wave][edge][head]

  float4 ad = a_dst[n];
  float m0=-INFINITY, m1=-INFINITY, m2=-INFINITY, m3=-INFINITY;
  float4 l4 = make_float4(0.f,0.f,0.f,0.f);
  float acc[8];
  #pragma unroll
  for (int k=0;k<8;k++) acc[k]=0.f;

  int beg = row_start[n];
  int deg = row_start[n+1] - beg;

  for (int cb = 0; cb < deg; cb += 64) {
    int cnt = min(64, deg - cb);
    int s = 0;
    float4 e = make_float4(-INFINITY,-INFINITY,-INFINITY,-INFINITY);
    if (lane < cnt) {
      s = csr[beg + cb + lane];
      float4 as = a_src[s];
      e.x = lrelu(as.x + ad.x);
      e.y = lrelu(as.y + ad.y);
      e.z = lrelu(as.z + ad.z);
      e.w = lrelu(as.w + ad.w);
    }
    float4 cm = e;
    #pragma unroll
    for (int d=32; d>=1; d>>=1) {
      cm.x = fmaxf(cm.x, __shfl_xor(cm.x, d));
      cm.y = fmaxf(cm.y, __shfl_xor(cm.y, d));
      cm.z = fmaxf(cm.z, __shfl_xor(cm.z, d));
      cm.w = fmaxf(cm.w, __shfl_xor(cm.w, d));
    }
    float nm0 = fmaxf(m0, cm.x), nm1 = fmaxf(m1, cm.y);
    float nm2 = fmaxf(m2, cm.z), nm3 = fmaxf(m3, cm.w);
    float sc0 = __expf(m0-nm0), sc1 = __expf(m1-nm1);
    float sc2 = __expf(m2-nm2), sc3 = __expf(m3-nm3);
    m0=nm0; m1=nm1; m2=nm2; m3=nm3;
    float sch = hd8==0 ? sc0 : hd8==1 ? sc1 : hd8==2 ? sc2 : sc3;
    #pragma unroll
    for (int k=0;k<8;k++) acc[k] *= sch;
    float4 p = make_float4(0.f,0.f,0.f,0.f);
    if (lane < cnt) {
      p.x = __expf(e.x - nm0);
      p.y = __expf(e.y - nm1);
      p.z = __expf(e.z - nm2);
      p.w = __expf(e.w - nm3);
    }
    l4.x = l4.x*sc0 + p.x;
    l4.y = l4.y*sc1 + p.y;
    l4.z = l4.z*sc2 + p.z;
    l4.w = l4.w*sc3 + p.w;
    st4(&s_p[w][lane][0], p);          // wave-local
    int pairs = (cnt + 1) >> 1;
    for (int j2 = 0; j2 < pairs; j2++) {
      int jj = 2*j2 + half;
      int sj = __shfl(s, jj & 63);
      if (jj < cnt) {
        float pw = s_p[w][jj][hd8];
        uint4 u = *(const uint4*)&hbf[(size_t)sj*HC + c0];
        acc[0] += pw*bflo(u.x); acc[1] += pw*bfhi(u.x);
        acc[2] += pw*bflo(u.y); acc[3] += pw*bfhi(u.y);
        acc[4] += pw*bflo(u.z); acc[5] += pw*bfhi(u.z);
        acc[6] += pw*bflo(u.w); acc[7] += pw*bfhi(u.w);
      }
    }
  }
  #pragma unroll
  for (int d=32; d>=1; d>>=1) {
    l4.x += __shfl_xor(l4.x, d);
    l4.y += __shfl_xor(l4.y, d);
    l4.z += __shfl_xor(l4.z, d);
    l4.w += __shfl_xor(l4.w, d);
  }
  #pragma unroll
  for (int k=0;k<8;k++) acc[k] += __shfl_xor(acc[k], 32);
  float lh = hd8==0 ? l4.x : hd8==1 ? l4.y : hd8==2 ? l4.z : l4.w;
  float inv = 1.f / lh;
  int kb = half * 4;
  float4 b = ld4(&bias[c0 + kb]);
  float4 r;
  r.x = fmaxf(acc[kb+0]*inv + b.x, 0.f);
  r.y = fmaxf(acc[kb+1]*inv + b.y, 0.f);
  r.z = fmaxf(acc[kb+2]*inv + b.z, 0.f);
  r.w = fmaxf(acc[kb+3]*inv + b.w, 0.f);
  st4(&out_conv[(size_t)n*HC + c0 + kb], r);
}

// ---------------- lin1: hid = relu(X@W1 + b1)  [M,256]x[256,64] ----------------
#define BM 64
#define BK 16
__global__ __launch_bounds__(256) void k_lin1(const float* __restrict__ A,
    const float* __restrict__ B, const float* __restrict__ b1,
    float* __restrict__ C, int M) {
  __shared__ float As[BK][BM+4];
  __shared__ float Bs[BK][68];
  int t = threadIdx.x;
  int tx = t & 15, ty = t >> 4;
  int row0 = blockIdx.x * BM;
  float acc[4][4];
  #pragma unroll
  for (int i=0;i<4;i++)
    #pragma unroll
    for (int j=0;j<4;j++) acc[i][j]=0.f;
  int lm = t >> 2, lk = (t & 3) * 4;
  int br = t >> 4, bc = (t & 15) * 4;
  for (int kk = 0; kk < 256; kk += BK) {
    float4 av = make_float4(0.f,0.f,0.f,0.f);
    if (row0 + lm < M) av = ld4(&A[(size_t)(row0+lm)*256 + kk + lk]);
    As[lk+0][lm]=av.x; As[lk+1][lm]=av.y; As[lk+2][lm]=av.z; As[lk+3][lm]=av.w;
    st4(&Bs[br][bc], ld4(&B[(size_t)(kk+br)*64 + bc]));
    __syncthreads();
    #pragma unroll
    for (int k=0;k<BK;k++){
      float ar[4], brr[4];
      #pragma unroll
      for (int i=0;i<4;i++) ar[i]=As[k][ty*4+i];
      #pragma unroll
      for (int j=0;j<4;j++) brr[j]=Bs[k][tx*4+j];
      #pragma unroll
      for (int i=0;i<4;i++)
        #pragma unroll
        for (int j=0;j<4;j++)
          acc[i][j] += ar[i]*brr[j];
    }
    __syncthreads();
  }
  float4 bb = ld4(&b1[tx*4]);
  #pragma unroll
  for (int i=0;i<4;i++){
    int row = row0 + ty*4 + i;
    if (row < M) {
      float4 v = make_float4(fmaxf(acc[i][0]+bb.x,0.f), fmaxf(acc[i][1]+bb.y,0.f),
                             fmaxf(acc[i][2]+bb.z,0.f), fmaxf(acc[i][3]+bb.w,0.f));
      st4(&C[(size_t)row*64 + tx*4], v);
    }
  }
}

// ---------------- lin2: out = hid@W2 + b2  [M,64]x[64,40] ----------------
__global__ __launch_bounds__(256, 4) void k_lin2(const float* __restrict__ Hd,
    const float* __restrict__ W2, const float* __restrict__ b2,
    float* __restrict__ out, int M) {
  __shared__ float Hs[64][68];
  __shared__ float W2s[64][44];
  int t = threadIdx.x;
  int rowb = blockIdx.x * 64;
  #pragma unroll
  for (int i=0;i<3;i++){
    int idx = t + 256*i;
    if (idx < 640) {
      int k = idx/10, c4 = (idx%10)*4;
      st4(&W2s[k][c4], ld4(&W2[(size_t)k*40 + c4]));
    }
  }
  #pragma unroll
  for (int i=0;i<4;i++){
    int idx = t + 256*i;
    int r = idx >> 4, c4 = (idx & 15)*4;
    float4 v = make_float4(0.f,0.f,0.f,0.f);
    if (rowb + r < M) v = ld4(&Hd[(size_t)(rowb+r)*64 + c4]);
    st4(&Hs[r][c4], v);
  }
  __syncthreads();
  int tx = t & 15, ty = t >> 4;
  if (tx < 10) {
    float acc[4][4];
    #pragma unroll
    for (int i=0;i<4;i++)
      #pragma unroll
      for (int j=0;j<4;j++) acc[i][j]=0.f;
    #pragma unroll 2
    for (int k4=0;k4<16;k4++){
      float4 a[4], wv[4];
      #pragma unroll
      for (int i=0;i<4;i++) a[i] = ld4(&Hs[ty*4+i][k4*4]);
      #pragma unroll
      for (int kk=0;kk<4;kk++) wv[kk] = ld4(&W2s[k4*4+kk][tx*4]);
      #pragma unroll
      for (int i=0;i<4;i++){
        acc[i][0] += a[i].x*wv[0].x + a[i].y*wv[1].x + a[i].z*wv[2].x + a[i].w*wv[3].x;
        acc[i][1] += a[i].x*wv[0].y + a[i].y*wv[1].y + a[i].z*wv[2].y + a[i].w*wv[3].y;
        acc[i][2] += a[i].x*wv[0].z + a[i].y*wv[1].z + a[i].z*wv[2].z + a[i].w*wv[3].z;
        acc[i][3] += a[i].x*wv[0].w + a[i].y*wv[1].w + a[i].z*wv[2].w + a[i].w*wv[3].w;
      }
    }
    float4 bb = ld4(&b2[tx*4]);
    #pragma unroll
    for (int i=0;i<4;i++){
      int row = rowb + ty*4 + i;
      if (row < M) {
        float4 v = make_float4(acc[i][0]+bb.x, acc[i][1]+bb.y,
                               acc[i][2]+bb.z, acc[i][3]+bb.w);
        st4(&out[(size_t)row*40 + tx*4], v);
      }
    }
  }
}

extern "C" void kernel_launch(void* const* d_in, const int* in_sizes, int n_in,
                              void* d_out, int out_size, void* d_ws, size_t ws_size,
                              hipStream_t stream) {
  const int Nn = in_sizes[0] / HC;   // 50000
  const int E  = in_sizes[1] / 2;    // 800000
  const float* x        = (const float*)d_in[0];
  const int*   ei       = (const int*)d_in[1];
  const float* W        = (const float*)d_in[2];
  const float* att_src  = (const float*)d_in[3];
  const float* att_dst  = (const float*)d_in[4];
  const float* biasconv = (const float*)d_in[5];
  const float* W1       = (const float*)d_in[6];
  const float* b1       = (const float*)d_in[7];
  const float* W2       = (const float*)d_in[8];
  const float* b2       = (const float*)d_in[9];
  float* out = (float*)d_out;

  size_t off = 0;
  auto alloc = [&](size_t bytes)->void* {
    void* p = (void*)((char*)d_ws + off);
    off += (bytes + 255) & ~(size_t)255;
    return p;
  };
  unsigned short* hbf = (unsigned short*)alloc((size_t)Nn*HC*sizeof(unsigned short));
  unsigned short* Bhi = (unsigned short*)alloc((size_t)256*256*sizeof(unsigned short));
  unsigned short* Blo = (unsigned short*)alloc((size_t)256*256*sizeof(unsigned short));
  float* outc     = (float*)alloc((size_t)Nn*HC*sizeof(float));
  float* hid      = (float*)alloc((size_t)Nn*64*sizeof(float));
  float* a_src_v  = (float*)alloc((size_t)Nn*4*sizeof(float));
  float* a_dst_v  = (float*)alloc((size_t)Nn*4*sizeof(float));
  int*   count    = (int*)alloc((size_t)Nn*sizeof(int));
  int*   rowstart = (int*)alloc((size_t)(Nn+1)*sizeof(int));
  int*   cursor   = (int*)alloc((size_t)Nn*sizeof(int));
  int*   partial  = (int*)alloc(256*sizeof(int));
  int*   csr      = (int*)alloc((size_t)(E+Nn)*sizeof(int));
  (void)ws_size; (void)n_in; (void)out_size;

  dim3 blk(256);
  k_splitB<<<dim3(256), blk, 0, stream>>>(W, Bhi, Blo);
  k_gemm1<<<dim3(2, (Nn+127)/128), blk, 0, stream>>>(x, Bhi, Blo, hbf, Nn);
  k_attn<<<dim3((Nn*32+255)/256), blk, 0, stream>>>(hbf, att_src, att_dst, a_src_v, a_dst_v, Nn);
  k_init_count<<<dim3((Nn+255)/256), blk, 0, stream>>>(count, Nn);
  k_count<<<dim3((E+255)/256), blk, 0, stream>>>(ei, count, E);
  int nb = (Nn+255)/256;
  k_scan1<<<dim3(nb), blk, 0, stream>>>(count, rowstart, partial, Nn);
  k_scan2<<<dim3(1), blk, 0, stream>>>(partial, nb);
  k_scan3<<<dim3(nb), blk, 0, stream>>>(rowstart, cursor, partial, count, Nn);
  k_fill<<<dim3((E+Nn+255)/256), blk, 0, stream>>>(ei, cursor, csr, E, Nn);
  k_gat<<<dim3(Nn/4), blk, 0, stream>>>(hbf, (const float4*)a_src_v, (const float4*)a_dst_v,
                                        rowstart, csr, biasconv, outc);
  k_lin1<<<dim3((Nn+BM-1)/BM), blk, 0, stream>>>(outc, W1, b1, hid, Nn);
  k_lin2<<<dim3((Nn+63)/64), blk, 0, stream>>>(hid, W2, b2, out, Nn);
}

// Round 6
// 368.102 us; speedup vs baseline: 1.4904x; 1.0665x over previous
//
#include <hip/hip_runtime.h>
#include <math.h>

#define HEADS 4
#define CH 64
#define HC 256          // HEADS*CH
#define SLOPE 0.2f

typedef __attribute__((ext_vector_type(8))) short bf16x8;
typedef __attribute__((ext_vector_type(4))) float f32x4;

__device__ __forceinline__ float4 ld4(const float* p){ return *(const float4*)p; }
__device__ __forceinline__ void st4(float* p, float4 v){ *(float4*)p = v; }
__device__ __forceinline__ float lrelu(float x){ return x > 0.f ? x : SLOPE * x; }
__device__ __forceinline__ unsigned short f2bf(float f){
  union { float f; unsigned int u; } v; v.f = f;
  unsigned int r = v.u + 0x7fffu + ((v.u >> 16) & 1u);   // RNE
  return (unsigned short)(r >> 16);
}
__device__ __forceinline__ float bflo(unsigned int u){
  union { unsigned int u; float f; } v; v.u = u << 16; return v.f;
}
__device__ __forceinline__ float bfhi(unsigned int u){
  union { unsigned int u; float f; } v; v.u = u & 0xffff0000u; return v.f;
}
// async global->LDS DMA, 16B per lane; LDS dest = wave-uniform base + lane*16
__device__ __forceinline__ void dma16(const unsigned short* g, unsigned short* l){
  __builtin_amdgcn_global_load_lds(
      (const __attribute__((address_space(1))) unsigned int*)g,
      (__attribute__((address_space(3))) unsigned int*)l, 16, 0, 0);
}

// ---------------- split x into bf16 hi/lo [Mpad][256] ----------------
__global__ __launch_bounds__(256) void k_splitA(const float* __restrict__ x,
    unsigned short* __restrict__ hi, unsigned short* __restrict__ lo, int nf4) {
  int idx = blockIdx.x*256 + threadIdx.x;
  if (idx >= nf4) return;
  float4 v = ld4(&x[(size_t)idx*4]);
  unsigned int ux = __float_as_uint(v.x), uy = __float_as_uint(v.y);
  unsigned int uz = __float_as_uint(v.z), uw = __float_as_uint(v.w);
  ushort4 h;
  h.x = (unsigned short)(ux>>16); h.y = (unsigned short)(uy>>16);
  h.z = (unsigned short)(uz>>16); h.w = (unsigned short)(uw>>16);
  float lx = v.x - __uint_as_float(ux & 0xffff0000u);
  float ly = v.y - __uint_as_float(uy & 0xffff0000u);
  float lz = v.z - __uint_as_float(uz & 0xffff0000u);
  float lw = v.w - __uint_as_float(uw & 0xffff0000u);
  ushort4 l;
  l.x = (unsigned short)(__float_as_uint(lx)>>16);
  l.y = (unsigned short)(__float_as_uint(ly)>>16);
  l.z = (unsigned short)(__float_as_uint(lz)>>16);
  l.w = (unsigned short)(__float_as_uint(lw)>>16);
  *(ushort4*)&hi[(size_t)idx*4] = h;
  *(ushort4*)&lo[(size_t)idx*4] = l;
}

// ---------------- split W into bf16 hi/lo, transposed to [N][K] ----------------
__global__ __launch_bounds__(256) void k_splitB(const float* __restrict__ W,
    unsigned short* __restrict__ hi, unsigned short* __restrict__ lo) {
  int n = blockIdx.x, k = threadIdx.x;
  float v = W[(size_t)k*256 + n];
  unsigned int u = __float_as_uint(v);
  hi[(size_t)n*256 + k] = (unsigned short)(u >> 16);
  float hf = __uint_as_float(u & 0xffff0000u);
  lo[(size_t)n*256 + k] = (unsigned short)(__float_as_uint(v - hf) >> 16);
}

// ---------------- GEMM1: hbf = bf16(x @ W), 3-pass split-bf16 MFMA ----------------
// 128x128 tile, BK=32, 8 chunks; 4 x 8KB LDS buffers filled by global_load_lds
// with source-side XOR swizzle. Frag reads land 2 lanes/bank (free).
__global__ __launch_bounds__(256, 4) void k_gemm1(const unsigned short* __restrict__ Ahi,
    const unsigned short* __restrict__ Alo,
    const unsigned short* __restrict__ Bhi_t, const unsigned short* __restrict__ Blo_t,
    unsigned short* __restrict__ hbf, int M) {
  __shared__ __align__(16) unsigned short L[4*4096];  // Ah | Al | Bh | Bl, 4096 shorts each
  int t = threadIdx.x;
  int lane = t & 63, w = t >> 6;
  int wr = w >> 1, wc = w & 1;
  int ln15 = lane & 15, lq = lane >> 4;
  int row0 = blockIdx.y * 128, col0 = blockIdx.x * 128;

  f32x4 acc[4][4];
  #pragma unroll
  for (int i=0;i<4;i++)
    #pragma unroll
    for (int j=0;j<4;j++) acc[i][j] = (f32x4){0.f,0.f,0.f,0.f};

  // precompute DMA slot geometry (two issues per wave per buffer)
  // slot s: R=s>>3, v=s&7, u=v^(R&7) -> idx=2R|(u&1), seg=u>>1
  int sA = w*128 + lane;               // issue 0
  int sB = sA + 64;                    // issue 1
  int RA = sA>>3, uA = (sA&7)^(RA&7), idxA = (RA<<1)|(uA&1), segA = uA>>1;
  int RB = sB>>3, uB = (sB&7)^(RB&7), idxB = (RB<<1)|(uB&1), segB = uB>>1;
  size_t gA_a = (size_t)(row0+idxA)*256 + segA*8;   // + k0
  size_t gA_b = (size_t)(row0+idxB)*256 + segB*8;
  size_t gB_a = (size_t)(col0+idxA)*256 + segA*8;
  size_t gB_b = (size_t)(col0+idxB)*256 + segB*8;
  int l0 = (w*128)*8, l1 = (w*128+64)*8;            // LDS short-offsets per issue

  for (int c = 0; c < 8; c++) {
    int k0 = c*32;
    dma16(Ahi   + gA_a + k0, &L[0*4096 + l0]);
    dma16(Ahi   + gA_b + k0, &L[0*4096 + l1]);
    dma16(Alo   + gA_a + k0, &L[1*4096 + l0]);
    dma16(Alo   + gA_b + k0, &L[1*4096 + l1]);
    dma16(Bhi_t + gB_a + k0, &L[2*4096 + l0]);
    dma16(Bhi_t + gB_b + k0, &L[2*4096 + l1]);
    dma16(Blo_t + gB_a + k0, &L[3*4096 + l0]);
    dma16(Blo_t + gB_b + k0, &L[3*4096 + l1]);
    __syncthreads();   // drains vmcnt -> DMA complete for all waves

    bf16x8 bh[4], bl[4];
    #pragma unroll
    for (int j = 0; j < 4; j++) {
      int n = wc*64 + j*16 + ln15;
      int R = n >> 1, u = (lq << 1) | (n & 1);
      int s = R*8 + (u ^ (R & 7));
      bh[j] = *(bf16x8*)&L[2*4096 + s*8];
      bl[j] = *(bf16x8*)&L[3*4096 + s*8];
    }
    #pragma unroll
    for (int i = 0; i < 4; i++) {
      int r = wr*64 + i*16 + ln15;
      int R = r >> 1, u = (lq << 1) | (r & 1);
      int s = R*8 + (u ^ (R & 7));
      bf16x8 ah = *(bf16x8*)&L[0*4096 + s*8];
      bf16x8 al = *(bf16x8*)&L[1*4096 + s*8];
      #pragma unroll
      for (int j = 0; j < 4; j++) {
        acc[i][j] = __builtin_amdgcn_mfma_f32_16x16x32_bf16(ah, bh[j], acc[i][j], 0,0,0);
        acc[i][j] = __builtin_amdgcn_mfma_f32_16x16x32_bf16(al, bh[j], acc[i][j], 0,0,0);
        acc[i][j] = __builtin_amdgcn_mfma_f32_16x16x32_bf16(ah, bl[j], acc[i][j], 0,0,0);
      }
    }
    __syncthreads();   // reads done before next chunk's DMA overwrites
  }
  // ---- epilogue: C/D layout col=lane&15, row=(lane>>4)*4+reg (verified R3-R5) ----
  #pragma unroll
  for (int i = 0; i < 4; i++) {
    #pragma unroll
    for (int r = 0; r < 4; r++) {
      int row = row0 + wr*64 + i*16 + lq*4 + r;
      if (row < M) {
        #pragma unroll
        for (int j = 0; j < 4; j++) {
          int col = col0 + wc*64 + j*16 + ln15;
          hbf[(size_t)row*HC + col] = f2bf(acc[i][j][r]);
        }
      }
    }
  }
}

// ---------------- attention coefficients from bf16 h: a_src/a_dst [N,4] ----------------
__global__ __launch_bounds__(256) void k_attn(const unsigned short* __restrict__ hbf,
    const float* __restrict__ att_src, const float* __restrict__ att_dst,
    float* __restrict__ a_src, float* __restrict__ a_dst, int n) {
  int gid = blockIdx.x*256 + threadIdx.x;
  int node = gid >> 5;
  int sl = gid & 31;
  if (node >= n) return;
  int c0 = sl*8, head = sl >> 3;
  uint4 u = *(const uint4*)&hbf[(size_t)node*HC + c0];
  float v0 = bflo(u.x), v1 = bfhi(u.x), v2 = bflo(u.y), v3 = bfhi(u.y);
  float v4 = bflo(u.z), v5 = bfhi(u.z), v6 = bflo(u.w), v7 = bfhi(u.w);
  const float* as = &att_src[head*CH + (sl&7)*8];
  const float* ad = &att_dst[head*CH + (sl&7)*8];
  float4 a0 = ld4(as), a1 = ld4(as+4);
  float4 d0 = ld4(ad), d1 = ld4(ad+4);
  float ps = v0*a0.x + v1*a0.y + v2*a0.z + v3*a0.w
           + v4*a1.x + v5*a1.y + v6*a1.z + v7*a1.w;
  float pd = v0*d0.x + v1*d0.y + v2*d0.z + v3*d0.w
           + v4*d1.x + v5*d1.y + v6*d1.z + v7*d1.w;
  #pragma unroll
  for (int m=4; m>=1; m>>=1) { ps += __shfl_xor(ps, m); pd += __shfl_xor(pd, m); }
  if ((sl & 7) == 0) { a_src[node*4+head] = ps; a_dst[node*4+head] = pd; }
}

// ---------------- CSR build ----------------
__global__ void k_init_count(int* __restrict__ count, int n) {
  int i = blockIdx.x*256 + threadIdx.x;
  if (i < n) count[i] = 1;               // self-loop
}
__global__ void k_count(const int* __restrict__ ei, int* __restrict__ count, int E) {
  int e = blockIdx.x*256 + threadIdx.x;
  if (e < E) atomicAdd(&count[ei[E+e]], 1);
}
__global__ __launch_bounds__(256) void k_scan1(const int* __restrict__ count,
    int* __restrict__ excl, int* __restrict__ partial, int n) {
  __shared__ int sd[256];
  int t = threadIdx.x, i = blockIdx.x*256 + t;
  int v = (i < n) ? count[i] : 0;
  sd[t] = v; __syncthreads();
  for (int off=1; off<256; off<<=1) {
    int x = (t >= off) ? sd[t-off] : 0;
    __syncthreads();
    sd[t] += x;
    __syncthreads();
  }
  if (i < n) excl[i] = sd[t] - v;
  if (t == 255) partial[blockIdx.x] = sd[255];
}
__global__ __launch_bounds__(256) void k_scan2(int* __restrict__ partial, int nb) {
  __shared__ int sd[256];
  int t = threadIdx.x;
  int v = (t < nb) ? partial[t] : 0;
  sd[t] = v; __syncthreads();
  for (int off=1; off<256; off<<=1) {
    int x = (t >= off) ? sd[t-off] : 0;
    __syncthreads();
    sd[t] += x;
    __syncthreads();
  }
  partial[t] = sd[t] - v;
}
__global__ void k_scan3(int* __restrict__ row_start, int* __restrict__ cursor,
    const int* __restrict__ partial, const int* __restrict__ count, int n) {
  int i = blockIdx.x*256 + threadIdx.x;
  if (i < n) {
    int v = row_start[i] + partial[blockIdx.x];
    row_start[i] = v;
    cursor[i] = v;
    if (i == n-1) row_start[n] = v + count[i];
  }
}
__global__ void k_fill(const int* __restrict__ ei, int* __restrict__ cursor,
    int* __restrict__ csr, int E, int n) {
  int t = blockIdx.x*256 + threadIdx.x;
  if (t < E + n) {
    int s, d;
    if (t < E) { s = ei[t]; d = ei[E+t]; } else { s = t - E; d = s; }
    int p = atomicAdd(&cursor[d], 1);
    csr[p] = s;
  }
}

// ---------------- GAT softmax + aggregate, one WAVE per dst node ----------------
__global__ __launch_bounds__(256) void k_gat(const unsigned short* __restrict__ hbf,
    const float4* __restrict__ a_src, const float4* __restrict__ a_dst,
    const int* __restrict__ row_start, const int* __restrict__ csr,
    const float* __restrict__ bias, float* __restrict__ out_conv) {
  int w = threadIdx.x >> 6, lane = threadIdx.x & 63;
  int n = blockIdx.x * 4 + w;          // grid = N/4 exactly
  int half = lane >> 5, cl = lane & 31;
  int c0 = cl * 8;                     // this lane's 8 channels
  int hd8 = cl >> 3;                   // head owning those channels

  __shared__ float s_p[4][64][4];      // [wave][edge][head]

  float4 ad = a_dst[n];
  float m0=-INFINITY, m1=-INFINITY, m2=-INFINITY, m3=-INFINITY;
  float4 l4 = make_float4(0.f,0.f,0.f,0.f);
  float acc[8];
  #pragma unroll
  for (int k=0;k<8;k++) acc[k]=0.f;

  int beg = row_start[n];
  int deg = row_start[n+1] - beg;

  for (int cb = 0; cb < deg; cb += 64) {
    int cnt = min(64, deg - cb);
    int s = 0;
    float4 e = make_float4(-INFINITY,-INFINITY,-INFINITY,-INFINITY);
    if (lane < cnt) {
      s = csr[beg + cb + lane];
      float4 as = a_src[s];
      e.x = lrelu(as.x + ad.x);
      e.y = lrelu(as.y + ad.y);
      e.z = lrelu(as.z + ad.z);
      e.w = lrelu(as.w + ad.w);
    }
    float4 cm = e;
    #pragma unroll
    for (int d=32; d>=1; d>>=1) {
      cm.x = fmaxf(cm.x, __shfl_xor(cm.x, d));
      cm.y = fmaxf(cm.y, __shfl_xor(cm.y, d));
      cm.z = fmaxf(cm.z, __shfl_xor(cm.z, d));
      cm.w = fmaxf(cm.w, __shfl_xor(cm.w, d));
    }
    float nm0 = fmaxf(m0, cm.x), nm1 = fmaxf(m1, cm.y);
    float nm2 = fmaxf(m2, cm.z), nm3 = fmaxf(m3, cm.w);
    float sc0 = __expf(m0-nm0), sc1 = __expf(m1-nm1);
    float sc2 = __expf(m2-nm2), sc3 = __expf(m3-nm3);
    m0=nm0; m1=nm1; m2=nm2; m3=nm3;
    float sch = hd8==0 ? sc0 : hd8==1 ? sc1 : hd8==2 ? sc2 : sc3;
    #pragma unroll
    for (int k=0;k<8;k++) acc[k] *= sch;
    float4 p = make_float4(0.f,0.f,0.f,0.f);
    if (lane < cnt) {
      p.x = __expf(e.x - nm0);
      p.y = __expf(e.y - nm1);
      p.z = __expf(e.z - nm2);
      p.w = __expf(e.w - nm3);
    }
    l4.x = l4.x*sc0 + p.x;
    l4.y = l4.y*sc1 + p.y;
    l4.z = l4.z*sc2 + p.z;
    l4.w = l4.w*sc3 + p.w;
    st4(&s_p[w][lane][0], p);          // wave-local
    int pairs = (cnt + 1) >> 1;
    for (int j2 = 0; j2 < pairs; j2++) {
      int jj = 2*j2 + half;
      int sj = __shfl(s, jj & 63);
      if (jj < cnt) {
        float pw = s_p[w][jj][hd8];
        uint4 u = *(const uint4*)&hbf[(size_t)sj*HC + c0];
        acc[0] += pw*bflo(u.x); acc[1] += pw*bfhi(u.x);
        acc[2] += pw*bflo(u.y); acc[3] += pw*bfhi(u.y);
        acc[4] += pw*bflo(u.z); acc[5] += pw*bfhi(u.z);
        acc[6] += pw*bflo(u.w); acc[7] += pw*bfhi(u.w);
      }
    }
  }
  #pragma unroll
  for (int d=32; d>=1; d>>=1) {
    l4.x += __shfl_xor(l4.x, d);
    l4.y += __shfl_xor(l4.y, d);
    l4.z += __shfl_xor(l4.z, d);
    l4.w += __shfl_xor(l4.w, d);
  }
  #pragma unroll
  for (int k=0;k<8;k++) acc[k] += __shfl_xor(acc[k], 32);
  float lh = hd8==0 ? l4.x : hd8==1 ? l4.y : hd8==2 ? l4.z : l4.w;
  float inv = 1.f / lh;
  int kb = half * 4;
  float4 b = ld4(&bias[c0 + kb]);
  float4 r;
  r.x = fmaxf(acc[kb+0]*inv + b.x, 0.f);
  r.y = fmaxf(acc[kb+1]*inv + b.y, 0.f);
  r.z = fmaxf(acc[kb+2]*inv + b.z, 0.f);
  r.w = fmaxf(acc[kb+3]*inv + b.w, 0.f);
  st4(&out_conv[(size_t)n*HC + c0 + kb], r);
}

// ---------------- lin1: hid = relu(X@W1 + b1)  [M,256]x[256,64] ----------------
#define BM 64
#define BK 16
__global__ __launch_bounds__(256) void k_lin1(const float* __restrict__ A,
    const float* __restrict__ B, const float* __restrict__ b1,
    float* __restrict__ C, int M) {
  __shared__ float As[BK][BM+4];
  __shared__ float Bs[BK][68];
  int t = threadIdx.x;
  int tx = t & 15, ty = t >> 4;
  int row0 = blockIdx.x * BM;
  float acc[4][4];
  #pragma unroll
  for (int i=0;i<4;i++)
    #pragma unroll
    for (int j=0;j<4;j++) acc[i][j]=0.f;
  int lm = t >> 2, lk = (t & 3) * 4;
  int br = t >> 4, bc = (t & 15) * 4;
  for (int kk = 0; kk < 256; kk += BK) {
    float4 av = make_float4(0.f,0.f,0.f,0.f);
    if (row0 + lm < M) av = ld4(&A[(size_t)(row0+lm)*256 + kk + lk]);
    As[lk+0][lm]=av.x; As[lk+1][lm]=av.y; As[lk+2][lm]=av.z; As[lk+3][lm]=av.w;
    st4(&Bs[br][bc], ld4(&B[(size_t)(kk+br)*64 + bc]));
    __syncthreads();
    #pragma unroll
    for (int k=0;k<BK;k++){
      float ar[4], brr[4];
      #pragma unroll
      for (int i=0;i<4;i++) ar[i]=As[k][ty*4+i];
      #pragma unroll
      for (int j=0;j<4;j++) brr[j]=Bs[k][tx*4+j];
      #pragma unroll
      for (int i=0;i<4;i++)
        #pragma unroll
        for (int j=0;j<4;j++)
          acc[i][j] += ar[i]*brr[j];
    }
    __syncthreads();
  }
  float4 bb = ld4(&b1[tx*4]);
  #pragma unroll
  for (int i=0;i<4;i++){
    int row = row0 + ty*4 + i;
    if (row < M) {
      float4 v = make_float4(fmaxf(acc[i][0]+bb.x,0.f), fmaxf(acc[i][1]+bb.y,0.f),
                             fmaxf(acc[i][2]+bb.z,0.f), fmaxf(acc[i][3]+bb.w,0.f));
      st4(&C[(size_t)row*64 + tx*4], v);
    }
  }
}

// ---------------- lin2: out = hid@W2 + b2  [M,64]x[64,40] ----------------
__global__ __launch_bounds__(256, 4) void k_lin2(const float* __restrict__ Hd,
    const float* __restrict__ W2, const float* __restrict__ b2,
    float* __restrict__ out, int M) {
  __shared__ float Hs[64][68];
  __shared__ float W2s[64][44];
  int t = threadIdx.x;
  int rowb = blockIdx.x * 64;
  #pragma unroll
  for (int i=0;i<3;i++){
    int idx = t + 256*i;
    if (idx < 640) {
      int k = idx/10, c4 = (idx%10)*4;
      st4(&W2s[k][c4], ld4(&W2[(size_t)k*40 + c4]));
    }
  }
  #pragma unroll
  for (int i=0;i<4;i++){
    int idx = t + 256*i;
    int r = idx >> 4, c4 = (idx & 15)*4;
    float4 v = make_float4(0.f,0.f,0.f,0.f);
    if (rowb + r < M) v = ld4(&Hd[(size_t)(rowb+r)*64 + c4]);
    st4(&Hs[r][c4], v);
  }
  __syncthreads();
  int tx = t & 15, ty = t >> 4;
  if (tx < 10) {
    float acc[4][4];
    #pragma unroll
    for (int i=0;i<4;i++)
      #pragma unroll
      for (int j=0;j<4;j++) acc[i][j]=0.f;
    #pragma unroll 2
    for (int k4=0;k4<16;k4++){
      float4 a[4], wv[4];
      #pragma unroll
      for (int i=0;i<4;i++) a[i] = ld4(&Hs[ty*4+i][k4*4]);
      #pragma unroll
      for (int kk=0;kk<4;kk++) wv[kk] = ld4(&W2s[k4*4+kk][tx*4]);
      #pragma unroll
      for (int i=0;i<4;i++){
        acc[i][0] += a[i].x*wv[0].x + a[i].y*wv[1].x + a[i].z*wv[2].x + a[i].w*wv[3].x;
        acc[i][1] += a[i].x*wv[0].y + a[i].y*wv[1].y + a[i].z*wv[2].y + a[i].w*wv[3].y;
        acc[i][2] += a[i].x*wv[0].z + a[i].y*wv[1].z + a[i].z*wv[2].z + a[i].w*wv[3].z;
        acc[i][3] += a[i].x*wv[0].w + a[i].y*wv[1].w + a[i].z*wv[2].w + a[i].w*wv[3].w;
      }
    }
    float4 bb = ld4(&b2[tx*4]);
    #pragma unroll
    for (int i=0;i<4;i++){
      int row = rowb + ty*4 + i;
      if (row < M) {
        float4 v = make_float4(acc[i][0]+bb.x, acc[i][1]+bb.y,
                               acc[i][2]+bb.z, acc[i][3]+bb.w);
        st4(&out[(size_t)row*40 + tx*4], v);
      }
    }
  }
}

extern "C" void kernel_launch(void* const* d_in, const int* in_sizes, int n_in,
                              void* d_out, int out_size, void* d_ws, size_t ws_size,
                              hipStream_t stream) {
  const int Nn = in_sizes[0] / HC;   // 50000
  const int E  = in_sizes[1] / 2;    // 800000
  const int Mpad = (Nn + 127) & ~127;
  const float* x        = (const float*)d_in[0];
  const int*   ei       = (const int*)d_in[1];
  const float* W        = (const float*)d_in[2];
  const float* att_src  = (const float*)d_in[3];
  const float* att_dst  = (const float*)d_in[4];
  const float* biasconv = (const float*)d_in[5];
  const float* W1       = (const float*)d_in[6];
  const float* b1       = (const float*)d_in[7];
  const float* W2       = (const float*)d_in[8];
  const float* b2       = (const float*)d_in[9];
  float* out = (float*)d_out;

  size_t off = 0;
  auto alloc = [&](size_t bytes)->void* {
    void* p = (void*)((char*)d_ws + off);
    off += (bytes + 255) & ~(size_t)255;
    return p;
  };
  unsigned short* hbf = (unsigned short*)alloc((size_t)Nn*HC*sizeof(unsigned short));
  // union block: (Ahi|Alo) alias outc — disjoint lifetimes (Ahi/Alo die after gemm1;
  // outc born at k_gat)
  void* ublk = alloc((size_t)Mpad*HC*sizeof(float));
  unsigned short* Ahi = (unsigned short*)ublk;
  unsigned short* Alo = Ahi + (size_t)Mpad*HC;
  float* outc = (float*)ublk;
  unsigned short* Bhi = (unsigned short*)alloc((size_t)256*256*sizeof(unsigned short));
  unsigned short* Blo = (unsigned short*)alloc((size_t)256*256*sizeof(unsigned short));
  float* hid      = (float*)alloc((size_t)Nn*64*sizeof(float));
  float* a_src_v  = (float*)alloc((size_t)Nn*4*sizeof(float));
  float* a_dst_v  = (float*)alloc((size_t)Nn*4*sizeof(float));
  int*   count    = (int*)alloc((size_t)Nn*sizeof(int));
  int*   rowstart = (int*)alloc((size_t)(Nn+1)*sizeof(int));
  int*   cursor   = (int*)alloc((size_t)Nn*sizeof(int));
  int*   partial  = (int*)alloc(256*sizeof(int));
  int*   csr      = (int*)alloc((size_t)(E+Nn)*sizeof(int));
  (void)ws_size; (void)n_in; (void)out_size;

  dim3 blk(256);
  int nf4 = Nn*64;
  k_splitA<<<dim3((nf4+255)/256), blk, 0, stream>>>(x, Ahi, Alo, nf4);
  k_splitB<<<dim3(256), blk, 0, stream>>>(W, Bhi, Blo);
  k_gemm1<<<dim3(2, Mpad/128), blk, 0, stream>>>(Ahi, Alo, Bhi, Blo, hbf, Nn);
  k_attn<<<dim3((Nn*32+255)/256), blk, 0, stream>>>(hbf, att_src, att_dst, a_src_v, a_dst_v, Nn);
  k_init_count<<<dim3((Nn+255)/256), blk, 0, stream>>>(count, Nn);
  k_count<<<dim3((E+255)/256), blk, 0, stream>>>(ei, count, E);
  int nb = (Nn+255)/256;
  k_scan1<<<dim3(nb), blk, 0, stream>>>(count, rowstart, partial, Nn);
  k_scan2<<<dim3(1), blk, 0, stream>>>(partial, nb);
  k_scan3<<<dim3(nb), blk, 0, stream>>>(rowstart, cursor, partial, count, Nn);
  k_fill<<<dim3((E+Nn+255)/256), blk, 0, stream>>>(ei, cursor, csr, E, Nn);
  k_gat<<<dim3(Nn/4), blk, 0, stream>>>(hbf, (const float4*)a_src_v, (const float4*)a_dst_v,
                                        rowstart, csr, biasconv, outc);
  k_lin1<<<dim3((Nn+BM-1)/BM), blk, 0, stream>>>(outc, W1, b1, hid, Nn);
  k_lin2<<<dim3((Nn+63)/64), blk, 0, stream>>>(hid, W2, b2, out, Nn);
}

// Round 7
// 340.142 us; speedup vs baseline: 1.6129x; 1.0822x over previous
//
#include <hip/hip_runtime.h>
#include <math.h>

#define HEADS 4
#define CH 64
#define HC 256          // HEADS*CH
#define SLOPE 0.2f

typedef __attribute__((ext_vector_type(8))) short bf16x8;
typedef __attribute__((ext_vector_type(4))) float f32x4;

__device__ __forceinline__ float4 ld4(const float* p){ return *(const float4*)p; }
__device__ __forceinline__ void st4(float* p, float4 v){ *(float4*)p = v; }
__device__ __forceinline__ float lrelu(float x){ return x > 0.f ? x : SLOPE * x; }
__device__ __forceinline__ unsigned short f2bf(float f){
  union { float f; unsigned int u; } v; v.f = f;
  unsigned int r = v.u + 0x7fffu + ((v.u >> 16) & 1u);   // RNE
  return (unsigned short)(r >> 16);
}
__device__ __forceinline__ float bflo(unsigned int u){
  union { unsigned int u; float f; } v; v.u = u << 16; return v.f;
}
__device__ __forceinline__ float bfhi(unsigned int u){
  union { unsigned int u; float f; } v; v.u = u & 0xffff0000u; return v.f;
}
__device__ __forceinline__ void split2(float v, unsigned short& h, unsigned short& l){
  unsigned int u = __float_as_uint(v);
  h = (unsigned short)(u >> 16);
  float hf = __uint_as_float(u & 0xffff0000u);
  l = (unsigned short)(__float_as_uint(v - hf) >> 16);
}
// async global->LDS DMA, 16B/lane; LDS dest = wave-uniform base + lane*16
__device__ __forceinline__ void dma16(const unsigned short* g, unsigned short* l){
  __builtin_amdgcn_global_load_lds(
      (const __attribute__((address_space(1))) unsigned int*)g,
      (__attribute__((address_space(3))) unsigned int*)l, 16, 0, 0);
}

// ---------------- split x into bf16 hi/lo [Mpad][256] ----------------
__global__ __launch_bounds__(256) void k_splitA(const float* __restrict__ x,
    unsigned short* __restrict__ hi, unsigned short* __restrict__ lo, int nf4) {
  int idx = blockIdx.x*256 + threadIdx.x;
  if (idx >= nf4) return;
  float4 v = ld4(&x[(size_t)idx*4]);
  ushort4 h, l;
  split2(v.x, h.x, l.x); split2(v.y, h.y, l.y);
  split2(v.z, h.z, l.z); split2(v.w, h.w, l.w);
  *(ushort4*)&hi[(size_t)idx*4] = h;
  *(ushort4*)&lo[(size_t)idx*4] = l;
}

// ---------------- prep: split W (transposed), W1 (transposed), W2 (transposed+pad), init count ----
__global__ __launch_bounds__(256) void k_prep(const float* __restrict__ W,
    const float* __restrict__ W1, const float* __restrict__ W2,
    unsigned short* __restrict__ Bhi, unsigned short* __restrict__ Blo,
    unsigned short* __restrict__ W1h, unsigned short* __restrict__ W1l,
    unsigned short* __restrict__ W2h, unsigned short* __restrict__ W2l,
    int* __restrict__ count, int n) {
  int b = blockIdx.x, t = threadIdx.x;
  if (b < 256) {                       // W [256][256] -> [n][k]
    unsigned short h, l;
    split2(W[(size_t)t*256 + b], h, l);
    Bhi[(size_t)b*256 + t] = h; Blo[(size_t)b*256 + t] = l;
  } else if (b < 320) {                // W1 [256][64] -> [n][k]
    int nn = b - 256;
    unsigned short h, l;
    split2(W1[(size_t)t*64 + nn], h, l);
    W1h[(size_t)nn*256 + t] = h; W1l[(size_t)nn*256 + t] = l;
  } else if (b < 368) {                // W2 [64][40] -> [n pad48][k64]
    if (t < 64) {
      int nn = b - 320;
      float v = (nn < 40) ? W2[(size_t)t*40 + nn] : 0.f;
      unsigned short h, l;
      split2(v, h, l);
      W2h[(size_t)nn*64 + t] = h; W2l[(size_t)nn*64 + t] = l;
    }
  } else {                             // count init (self-loop)
    int i = (b - 368)*256 + t;
    if (i < n) count[i] = 1;
  }
}

// ---------------- GEMM1: hbf = bf16(x @ W), 3-pass split-bf16 MFMA + fused attn dots ----
__global__ __launch_bounds__(256, 4) void k_gemm1(const unsigned short* __restrict__ Ahi,
    const unsigned short* __restrict__ Alo,
    const unsigned short* __restrict__ Bhi_t, const unsigned short* __restrict__ Blo_t,
    unsigned short* __restrict__ hbf,
    const float* __restrict__ att_src, const float* __restrict__ att_dst,
    float* __restrict__ a_srcO, float* __restrict__ a_dstO, int M) {
  __shared__ __align__(16) unsigned short L[4*4096];  // Ah | Al | Bh | Bl
  int t = threadIdx.x;
  int lane = t & 63, w = t >> 6;
  int wr = w >> 1, wc = w & 1;
  int ln15 = lane & 15, lq = lane >> 4;
  int row0 = blockIdx.y * 128, col0 = blockIdx.x * 128;

  f32x4 acc[4][4];
  #pragma unroll
  for (int i=0;i<4;i++)
    #pragma unroll
    for (int j=0;j<4;j++) acc[i][j] = (f32x4){0.f,0.f,0.f,0.f};

  // DMA slot geometry (slot s: R=s>>3, u=(s&7)^(R&7) -> idx=2R|(u&1), seg=u>>1)
  int sA = w*128 + lane;
  int sB = sA + 64;
  int RA = sA>>3, uA = (sA&7)^(RA&7), idxA = (RA<<1)|(uA&1), segA = uA>>1;
  int RB = sB>>3, uB = (sB&7)^(RB&7), idxB = (RB<<1)|(uB&1), segB = uB>>1;
  size_t gA_a = (size_t)(row0+idxA)*256 + segA*8;
  size_t gA_b = (size_t)(row0+idxB)*256 + segB*8;
  size_t gB_a = (size_t)(col0+idxA)*256 + segA*8;
  size_t gB_b = (size_t)(col0+idxB)*256 + segB*8;
  int l0 = (w*128)*8, l1 = (w*128+64)*8;

  for (int c = 0; c < 8; c++) {
    int k0 = c*32;
    dma16(Ahi   + gA_a + k0, &L[0*4096 + l0]);
    dma16(Ahi   + gA_b + k0, &L[0*4096 + l1]);
    dma16(Alo   + gA_a + k0, &L[1*4096 + l0]);
    dma16(Alo   + gA_b + k0, &L[1*4096 + l1]);
    dma16(Bhi_t + gB_a + k0, &L[2*4096 + l0]);
    dma16(Bhi_t + gB_b + k0, &L[2*4096 + l1]);
    dma16(Blo_t + gB_a + k0, &L[3*4096 + l0]);
    dma16(Blo_t + gB_b + k0, &L[3*4096 + l1]);
    __syncthreads();

    bf16x8 bh[4], bl[4];
    #pragma unroll
    for (int j = 0; j < 4; j++) {
      int n = wc*64 + j*16 + ln15;
      int R = n >> 1, u = (lq << 1) | (n & 1);
      int s = R*8 + (u ^ (R & 7));
      bh[j] = *(bf16x8*)&L[2*4096 + s*8];
      bl[j] = *(bf16x8*)&L[3*4096 + s*8];
    }
    #pragma unroll
    for (int i = 0; i < 4; i++) {
      int r = wr*64 + i*16 + ln15;
      int R = r >> 1, u = (lq << 1) | (r & 1);
      int s = R*8 + (u ^ (R & 7));
      bf16x8 ah = *(bf16x8*)&L[0*4096 + s*8];
      bf16x8 al = *(bf16x8*)&L[1*4096 + s*8];
      #pragma unroll
      for (int j = 0; j < 4; j++) {
        acc[i][j] = __builtin_amdgcn_mfma_f32_16x16x32_bf16(ah, bh[j], acc[i][j], 0,0,0);
        acc[i][j] = __builtin_amdgcn_mfma_f32_16x16x32_bf16(al, bh[j], acc[i][j], 0,0,0);
        acc[i][j] = __builtin_amdgcn_mfma_f32_16x16x32_bf16(ah, bl[j], acc[i][j], 0,0,0);
      }
    }
    __syncthreads();
  }
  // ---- epilogue: store h bf16 (C/D: col=lane&15, row=(lane>>4)*4+reg) ----
  #pragma unroll
  for (int i = 0; i < 4; i++) {
    #pragma unroll
    for (int r = 0; r < 4; r++) {
      int row = row0 + wr*64 + i*16 + lq*4 + r;
      if (row < M) {
        #pragma unroll
        for (int j = 0; j < 4; j++) {
          int col = col0 + wc*64 + j*16 + ln15;
          hbf[(size_t)row*HC + col] = f2bf(acc[i][j][r]);
        }
      }
    }
  }
  // ---- fused attention dots: this wave's 64 cols == head ----
  int head = blockIdx.x*2 + wc;
  float asv[4], adv[4];
  #pragma unroll
  for (int j=0;j<4;j++){
    asv[j] = att_src[head*CH + j*16 + ln15];
    adv[j] = att_dst[head*CH + j*16 + ln15];
  }
  #pragma unroll
  for (int i = 0; i < 4; i++) {
    #pragma unroll
    for (int r = 0; r < 4; r++) {
      float ps = acc[i][0][r]*asv[0] + acc[i][1][r]*asv[1]
               + acc[i][2][r]*asv[2] + acc[i][3][r]*asv[3];
      float pd = acc[i][0][r]*adv[0] + acc[i][1][r]*adv[1]
               + acc[i][2][r]*adv[2] + acc[i][3][r]*adv[3];
      #pragma unroll
      for (int m=8; m>=1; m>>=1) { ps += __shfl_xor(ps, m); pd += __shfl_xor(pd, m); }
      if (ln15 == 0) {
        int row = row0 + wr*64 + i*16 + lq*4 + r;
        if (row < M) { a_srcO[row*4+head] = ps; a_dstO[row*4+head] = pd; }
      }
    }
  }
}

// ---------------- CSR build ----------------
__global__ void k_count(const int* __restrict__ ei, int* __restrict__ count, int E) {
  int e = blockIdx.x*256 + threadIdx.x;
  if (e < E) atomicAdd(&count[ei[E+e]], 1);
}
__global__ __launch_bounds__(256) void k_scan1(const int* __restrict__ count,
    int* __restrict__ excl, int* __restrict__ partial, int n) {
  __shared__ int sd[256];
  int t = threadIdx.x, i = blockIdx.x*256 + t;
  int v = (i < n) ? count[i] : 0;
  sd[t] = v; __syncthreads();
  for (int off=1; off<256; off<<=1) {
    int x = (t >= off) ? sd[t-off] : 0;
    __syncthreads();
    sd[t] += x;
    __syncthreads();
  }
  if (i < n) excl[i] = sd[t] - v;
  if (t == 255) partial[blockIdx.x] = sd[255];
}
__global__ __launch_bounds__(256) void k_scan2(int* __restrict__ partial, int nb) {
  __shared__ int sd[256];
  int t = threadIdx.x;
  int v = (t < nb) ? partial[t] : 0;
  sd[t] = v; __syncthreads();
  for (int off=1; off<256; off<<=1) {
    int x = (t >= off) ? sd[t-off] : 0;
    __syncthreads();
    sd[t] += x;
    __syncthreads();
  }
  partial[t] = sd[t] - v;
}
__global__ void k_scan3(int* __restrict__ row_start, int* __restrict__ cursor,
    const int* __restrict__ partial, const int* __restrict__ count, int n) {
  int i = blockIdx.x*256 + threadIdx.x;
  if (i < n) {
    int v = row_start[i] + partial[blockIdx.x];
    row_start[i] = v;
    cursor[i] = v;
    if (i == n-1) row_start[n] = v + count[i];
  }
}
__global__ void k_fill(const int* __restrict__ ei, int* __restrict__ cursor,
    int* __restrict__ csr, int E, int n) {
  int t = blockIdx.x*256 + threadIdx.x;
  if (t < E + n) {
    int s, d;
    if (t < E) { s = ei[t]; d = ei[E+t]; } else { s = t - E; d = s; }
    int p = atomicAdd(&cursor[d], 1);
    csr[p] = s;
  }
}

// ---------------- GAT softmax + aggregate, one WAVE per dst node; bf16 out ----------------
__global__ __launch_bounds__(256) void k_gat(const unsigned short* __restrict__ hbf,
    const float4* __restrict__ a_src, const float4* __restrict__ a_dst,
    const int* __restrict__ row_start, const int* __restrict__ csr,
    const float* __restrict__ bias, unsigned short* __restrict__ outbf) {
  int w = threadIdx.x >> 6, lane = threadIdx.x & 63;
  int n = blockIdx.x * 4 + w;          // grid = N/4 exactly
  int half = lane >> 5, cl = lane & 31;
  int c0 = cl * 8;
  int hd8 = cl >> 3;

  __shared__ float s_p[4][64][4];      // [wave][edge][head]

  float4 ad = a_dst[n];
  float m0=-INFINITY, m1=-INFINITY, m2=-INFINITY, m3=-INFINITY;
  float4 l4 = make_float4(0.f,0.f,0.f,0.f);
  float acc[8];
  #pragma unroll
  for (int k=0;k<8;k++) acc[k]=0.f;

  int beg = row_start[n];
  int deg = row_start[n+1] - beg;

  for (int cb = 0; cb < deg; cb += 64) {
    int cnt = min(64, deg - cb);
    int s = 0;
    float4 e = make_float4(-INFINITY,-INFINITY,-INFINITY,-INFINITY);
    if (lane < cnt) {
      s = csr[beg + cb + lane];
      float4 as = a_src[s];
      e.x = lrelu(as.x + ad.x);
      e.y = lrelu(as.y + ad.y);
      e.z = lrelu(as.z + ad.z);
      e.w = lrelu(as.w + ad.w);
    }
    float4 cm = e;
    #pragma unroll
    for (int d=32; d>=1; d>>=1) {
      cm.x = fmaxf(cm.x, __shfl_xor(cm.x, d));
      cm.y = fmaxf(cm.y, __shfl_xor(cm.y, d));
      cm.z = fmaxf(cm.z, __shfl_xor(cm.z, d));
      cm.w = fmaxf(cm.w, __shfl_xor(cm.w, d));
    }
    float nm0 = fmaxf(m0, cm.x), nm1 = fmaxf(m1, cm.y);
    float nm2 = fmaxf(m2, cm.z), nm3 = fmaxf(m3, cm.w);
    float sc0 = __expf(m0-nm0), sc1 = __expf(m1-nm1);
    float sc2 = __expf(m2-nm2), sc3 = __expf(m3-nm3);
    m0=nm0; m1=nm1; m2=nm2; m3=nm3;
    float sch = hd8==0 ? sc0 : hd8==1 ? sc1 : hd8==2 ? sc2 : sc3;
    #pragma unroll
    for (int k=0;k<8;k++) acc[k] *= sch;
    float4 p = make_float4(0.f,0.f,0.f,0.f);
    if (lane < cnt) {
      p.x = __expf(e.x - nm0);
      p.y = __expf(e.y - nm1);
      p.z = __expf(e.z - nm2);
      p.w = __expf(e.w - nm3);
    }
    l4.x = l4.x*sc0 + p.x;
    l4.y = l4.y*sc1 + p.y;
    l4.z = l4.z*sc2 + p.z;
    l4.w = l4.w*sc3 + p.w;
    st4(&s_p[w][lane][0], p);          // wave-local

    // 2-deep pipelined gather: prefetch pair j+1 while consuming pair j
    int pairs = (cnt + 1) >> 1;
    int jj = half;
    bool v0 = (jj < cnt);
    int sj = __shfl(s, jj & 63);
    uint4 u0 = make_uint4(0,0,0,0);
    if (v0) u0 = *(const uint4*)&hbf[(size_t)sj*HC + c0];
    for (int j2 = 0; j2 < pairs; j2++) {
      int jjn = jj + 2;
      bool vn = (j2+1 < pairs) && (jjn < cnt);
      int sjn = __shfl(s, jjn & 63);
      uint4 un = make_uint4(0,0,0,0);
      if (vn) un = *(const uint4*)&hbf[(size_t)sjn*HC + c0];
      if (v0) {
        float pw = s_p[w][jj][hd8];
        acc[0] += pw*bflo(u0.x); acc[1] += pw*bfhi(u0.x);
        acc[2] += pw*bflo(u0.y); acc[3] += pw*bfhi(u0.y);
        acc[4] += pw*bflo(u0.z); acc[5] += pw*bfhi(u0.z);
        acc[6] += pw*bflo(u0.w); acc[7] += pw*bfhi(u0.w);
      }
      u0 = un; v0 = vn; jj = jjn;
    }
  }
  #pragma unroll
  for (int d=32; d>=1; d>>=1) {
    l4.x += __shfl_xor(l4.x, d);
    l4.y += __shfl_xor(l4.y, d);
    l4.z += __shfl_xor(l4.z, d);
    l4.w += __shfl_xor(l4.w, d);
  }
  #pragma unroll
  for (int k=0;k<8;k++) acc[k] += __shfl_xor(acc[k], 32);
  float lh = hd8==0 ? l4.x : hd8==1 ? l4.y : hd8==2 ? l4.z : l4.w;
  float inv = 1.f / lh;
  int kb = half * 4;
  float4 b = ld4(&bias[c0 + kb]);
  ushort4 o;
  o.x = f2bf(fmaxf(acc[kb+0]*inv + b.x, 0.f));
  o.y = f2bf(fmaxf(acc[kb+1]*inv + b.y, 0.f));
  o.z = f2bf(fmaxf(acc[kb+2]*inv + b.z, 0.f));
  o.w = f2bf(fmaxf(acc[kb+3]*inv + b.w, 0.f));
  *(ushort4*)&outbf[(size_t)n*HC + c0 + kb] = o;
}

// ---------------- fused MLP: out = relu(Cbf@W1+b1)@W2+b2, MFMA ----------------
// 128 rows/block; A via DMA-swizzled LDS; W1/W2 frags direct from L2 (pre-split).
__global__ __launch_bounds__(256) void k_mlp(const unsigned short* __restrict__ Cbf,
    const unsigned short* __restrict__ W1h, const unsigned short* __restrict__ W1l,
    const unsigned short* __restrict__ W2h, const unsigned short* __restrict__ W2l,
    const float* __restrict__ b1, const float* __restrict__ b2,
    float* __restrict__ out, int M) {
  __shared__ __align__(16) unsigned short Abuf[4096];   // 128 rows x 32 k (slot-swizzled)
  __shared__ __align__(16) unsigned short Hs[128*72];   // hid bf16, stride 72
  int t = threadIdx.x, lane = t & 63, w = t >> 6;
  int ln15 = lane & 15, lq = lane >> 4;
  int row0 = blockIdx.x * 128;

  f32x4 acc1[2][4];
  #pragma unroll
  for (int i=0;i<2;i++)
    #pragma unroll
    for (int j=0;j<4;j++) acc1[i][j] = (f32x4){0.f,0.f,0.f,0.f};

  // slot s -> r=s>>2, seg=(s&3)^((r>>1)&3); frag slot(r,lq)=r*4+(lq^((r>>1)&3))
  int sA = w*64 + lane;          // issue 0
  int sB = 256 + w*64 + lane;    // issue 1
  int rA = sA >> 2, segA = (sA & 3) ^ ((rA >> 1) & 3);
  int rB = sB >> 2, segB = (sB & 3) ^ ((rB >> 1) & 3);
  size_t gA = (size_t)(row0 + rA) * 256 + segA*8;
  size_t gB = (size_t)(row0 + rB) * 256 + segB*8;
  int lA = (w*64)*8, lB = (256 + w*64)*8;

  for (int c = 0; c < 8; c++) {
    int k0 = c*32;
    dma16(Cbf + gA + k0, &Abuf[lA]);
    dma16(Cbf + gB + k0, &Abuf[lB]);
    __syncthreads();
    bf16x8 a[2];
    #pragma unroll
    for (int i = 0; i < 2; i++) {
      int r = w*32 + i*16 + ln15;
      int s = r*4 + (lq ^ ((r >> 1) & 3));
      a[i] = *(bf16x8*)&Abuf[s*8];
    }
    #pragma unroll
    for (int j = 0; j < 4; j++) {
      int n = j*16 + ln15;
      int k = k0 + lq*8;
      bf16x8 bh = *(const bf16x8*)&W1h[(size_t)n*256 + k];
      bf16x8 bl = *(const bf16x8*)&W1l[(size_t)n*256 + k];
      #pragma unroll
      for (int i = 0; i < 2; i++) {
        acc1[i][j] = __builtin_amdgcn_mfma_f32_16x16x32_bf16(a[i], bh, acc1[i][j], 0,0,0);
        acc1[i][j] = __builtin_amdgcn_mfma_f32_16x16x32_bf16(a[i], bl, acc1[i][j], 0,0,0);
      }
    }
    __syncthreads();
  }
  // bias + relu -> Hs (wave-local rows; no barrier needed)
  #pragma unroll
  for (int j = 0; j < 4; j++) {
    int col = j*16 + ln15;
    float bv = b1[col];
    #pragma unroll
    for (int i = 0; i < 2; i++) {
      #pragma unroll
      for (int r = 0; r < 4; r++) {
        int row = w*32 + i*16 + lq*4 + r;
        Hs[row*72 + col] = f2bf(fmaxf(acc1[i][j][r] + bv, 0.f));
      }
    }
  }
  // stage 2: hid @ W2 (N=48 padded, K=64)
  f32x4 acc2[2][3];
  #pragma unroll
  for (int i=0;i<2;i++)
    #pragma unroll
    for (int j=0;j<3;j++) acc2[i][j] = (f32x4){0.f,0.f,0.f,0.f};
  #pragma unroll
  for (int kf = 0; kf < 2; kf++) {
    bf16x8 a2[2];
    #pragma unroll
    for (int i = 0; i < 2; i++) {
      int m = w*32 + i*16 + ln15;
      a2[i] = *(bf16x8*)&Hs[m*72 + kf*32 + lq*8];
    }
    #pragma unroll
    for (int j = 0; j < 3; j++) {
      int n = j*16 + ln15;
      int k = kf*32 + lq*8;
      bf16x8 wh = *(const bf16x8*)&W2h[(size_t)n*64 + k];
      bf16x8 wl = *(const bf16x8*)&W2l[(size_t)n*64 + k];
      #pragma unroll
      for (int i = 0; i < 2; i++) {
        acc2[i][j] = __builtin_amdgcn_mfma_f32_16x16x32_bf16(a2[i], wh, acc2[i][j], 0,0,0);
        acc2[i][j] = __builtin_amdgcn_mfma_f32_16x16x32_bf16(a2[i], wl, acc2[i][j], 0,0,0);
      }
    }
  }
  // epilogue
  #pragma unroll
  for (int j = 0; j < 3; j++) {
    int col = j*16 + ln15;
    if (col < 40) {
      float bv = b2[col];
      #pragma unroll
      for (int i = 0; i < 2; i++) {
        #pragma unroll
        for (int r = 0; r < 4; r++) {
          int row = row0 + w*32 + i*16 + lq*4 + r;
          if (row < M) out[(size_t)row*40 + col] = acc2[i][j][r] + bv;
        }
      }
    }
  }
}

extern "C" void kernel_launch(void* const* d_in, const int* in_sizes, int n_in,
                              void* d_out, int out_size, void* d_ws, size_t ws_size,
                              hipStream_t stream) {
  const int Nn = in_sizes[0] / HC;   // 50000
  const int E  = in_sizes[1] / 2;    // 800000
  const int Mpad = (Nn + 127) & ~127;
  const float* x        = (const float*)d_in[0];
  const int*   ei       = (const int*)d_in[1];
  const float* W        = (const float*)d_in[2];
  const float* att_src  = (const float*)d_in[3];
  const float* att_dst  = (const float*)d_in[4];
  const float* biasconv = (const float*)d_in[5];
  const float* W1       = (const float*)d_in[6];
  const float* b1       = (const float*)d_in[7];
  const float* W2       = (const float*)d_in[8];
  const float* b2       = (const float*)d_in[9];
  float* out = (float*)d_out;

  size_t off = 0;
  auto alloc = [&](size_t bytes)->void* {
    void* p = (void*)((char*)d_ws + off);
    off += (bytes + 255) & ~(size_t)255;
    return p;
  };
  unsigned short* hbf = (unsigned short*)alloc((size_t)Nn*HC*sizeof(unsigned short));
  // union block: (Ahi|Alo) alias outc-bf16 — disjoint lifetimes
  void* ublk = alloc((size_t)Mpad*HC*sizeof(float));
  unsigned short* Ahi = (unsigned short*)ublk;
  unsigned short* Alo = Ahi + (size_t)Mpad*HC;
  unsigned short* outc = (unsigned short*)ublk;    // [Mpad][256] bf16
  unsigned short* Bhi = (unsigned short*)alloc((size_t)256*256*sizeof(unsigned short));
  unsigned short* Blo = (unsigned short*)alloc((size_t)256*256*sizeof(unsigned short));
  unsigned short* W1h = (unsigned short*)alloc((size_t)64*256*sizeof(unsigned short));
  unsigned short* W1l = (unsigned short*)alloc((size_t)64*256*sizeof(unsigned short));
  unsigned short* W2h = (unsigned short*)alloc((size_t)48*64*sizeof(unsigned short));
  unsigned short* W2l = (unsigned short*)alloc((size_t)48*64*sizeof(unsigned short));
  float* a_src_v  = (float*)alloc((size_t)Nn*4*sizeof(float));
  float* a_dst_v  = (float*)alloc((size_t)Nn*4*sizeof(float));
  int*   count    = (int*)alloc((size_t)Nn*sizeof(int));
  int*   rowstart = (int*)alloc((size_t)(Nn+1)*sizeof(int));
  int*   cursor   = (int*)alloc((size_t)Nn*sizeof(int));
  int*   partial  = (int*)alloc(256*sizeof(int));
  int*   csr      = (int*)alloc((size_t)(E+Nn)*sizeof(int));
  (void)ws_size; (void)n_in; (void)out_size;

  dim3 blk(256);
  int nf4 = Nn*64;
  int nb = (Nn+255)/256;
  k_splitA<<<dim3((nf4+255)/256), blk, 0, stream>>>(x, Ahi, Alo, nf4);
  k_prep<<<dim3(368 + nb), blk, 0, stream>>>(W, W1, W2, Bhi, Blo, W1h, W1l, W2h, W2l,
                                             count, Nn);
  k_gemm1<<<dim3(2, Mpad/128), blk, 0, stream>>>(Ahi, Alo, Bhi, Blo, hbf,
                                                 att_src, att_dst, a_src_v, a_dst_v, Nn);
  k_count<<<dim3((E+255)/256), blk, 0, stream>>>(ei, count, E);
  k_scan1<<<dim3(nb), blk, 0, stream>>>(count, rowstart, partial, Nn);
  k_scan2<<<dim3(1), blk, 0, stream>>>(partial, nb);
  k_scan3<<<dim3(nb), blk, 0, stream>>>(rowstart, cursor, partial, count, Nn);
  k_fill<<<dim3((E+Nn+255)/256), blk, 0, stream>>>(ei, cursor, csr, E, Nn);
  k_gat<<<dim3(Nn/4), blk, 0, stream>>>(hbf, (const float4*)a_src_v, (const float4*)a_dst_v,
                                        rowstart, csr, biasconv, outc);
  k_mlp<<<dim3(Mpad/128), blk, 0, stream>>>(outc, W1h, W1l, W2h, W2l, b1, b2, out, Nn);
}